// Round 1
// baseline (831.881 us; speedup 1.0000x reference)
//
#include <hip/hip_runtime.h>
#include <hip/hip_bf16.h>

typedef float v4 __attribute__((ext_vector_type(4)));

// ---------------- CSR build ----------------

__global__ __launch_bounds__(256) void init_kernel(int* counts, int* cursor, int N) {
    int i = blockIdx.x * 256 + threadIdx.x;
    if (i < N) { counts[i] = 1; /* self-loop */ cursor[i] = 0; }
}

__global__ __launch_bounds__(256) void hist_kernel(const int* __restrict__ dst, int* counts, int E) {
    int e = blockIdx.x * 256 + threadIdx.x;
    if (e < E) atomicAdd(&counts[dst[e]], 1);
}

__global__ __launch_bounds__(1024) void scan_kernel(const int* __restrict__ counts,
                                                    int* __restrict__ offsets, int n) {
    __shared__ int buf[1024];
    __shared__ int carry_s;
    int tid = threadIdx.x;
    if (tid == 0) carry_s = 0;
    __syncthreads();
    for (int base = 0; base < n; base += 1024) {
        int i = base + tid;
        int v = (i < n) ? counts[i] : 0;
        buf[tid] = v;
        __syncthreads();
        for (int off = 1; off < 1024; off <<= 1) {
            int t = (tid >= off) ? buf[tid - off] : 0;
            __syncthreads();
            buf[tid] += t;
            __syncthreads();
        }
        int incl = buf[tid];
        int carry = carry_s;
        if (i < n) offsets[i] = carry + incl - v;  // exclusive
        __syncthreads();
        if (tid == 1023) carry_s = carry + buf[1023];
        __syncthreads();
    }
    if (tid == 0) offsets[n] = carry_s;
}

__global__ __launch_bounds__(256) void scatter_kernel(const int* __restrict__ src,
                                                      const int* __restrict__ dst,
                                                      const int* __restrict__ offsets,
                                                      int* cursor, int* csr_src, int E, int N) {
    int id = blockIdx.x * 256 + threadIdx.x;
    if (id >= E + N) return;
    int d, s;
    if (id < E) { d = dst[id]; s = src[id]; }
    else        { d = id - E; s = d; }      // self-loop
    int pos = offsets[d] + atomicAdd(&cursor[d], 1);
    csr_src[pos] = s;
}

// ---------------- Layer 1 GEMM + attention dots ----------------
// xh1 = X@W1  [50000,64]@[64,256]; a_src1/a_dst1[n,h] = sum_c xh1[n,h,c]*att[h,c]
// block 256: tx = t&63 handles cols tx*4..tx*4+3; ty = t>>6 (= wave) handles nodes ty*4..ty*4+3

__global__ __launch_bounds__(256) void gemm1_att_kernel(
    const float* __restrict__ X, const float* __restrict__ W1,
    const float* __restrict__ att_src, const float* __restrict__ att_dst,
    float* __restrict__ xh1, float* __restrict__ a_src1, float* __restrict__ a_dst1)
{
    __shared__ __align__(16) float Ws[32 * 256];   // K-tile of W1 (32 rows), 32 KB
    __shared__ __align__(16) float Xs[16 * 36];    // 16 nodes x 32 k, pad to 36
    int t  = threadIdx.x;
    int tx = t & 63;
    int ty = t >> 6;
    int n0 = blockIdx.x * 16;

    v4 acc[4];
    #pragma unroll
    for (int n = 0; n < 4; n++) acc[n] = (v4)0.f;

    for (int kt = 0; kt < 64; kt += 32) {
        __syncthreads();
        {
            const float4* Wv = (const float4*)(W1 + kt * 256);
            float4* Wsv = (float4*)Ws;
            for (int i = t; i < 2048; i += 256) Wsv[i] = Wv[i];
        }
        for (int i = t; i < 16 * 32; i += 256) {
            int r = i >> 5, c = i & 31;
            Xs[r * 36 + c] = X[(size_t)(n0 + r) * 64 + kt + c];
        }
        __syncthreads();
        #pragma unroll
        for (int k4 = 0; k4 < 8; k4++) {
            v4 xv[4], wv[4];
            #pragma unroll
            for (int n = 0; n < 4; n++) xv[n] = *(const v4*)&Xs[(ty * 4 + n) * 36 + k4 * 4];
            #pragma unroll
            for (int kk = 0; kk < 4; kk++) wv[kk] = *(const v4*)&Ws[(k4 * 4 + kk) * 256 + tx * 4];
            #pragma unroll
            for (int n = 0; n < 4; n++)
                #pragma unroll
                for (int kk = 0; kk < 4; kk++)
                    acc[n] += xv[n][kk] * wv[kk];
        }
    }

    v4 asv = *(const v4*)&att_src[tx * 4];   // att_src1 flat [4*64], col j=h*64+c
    v4 adv = *(const v4*)&att_dst[tx * 4];
    #pragma unroll
    for (int n = 0; n < 4; n++) {
        int node = n0 + ty * 4 + n;
        *(v4*)&xh1[(size_t)node * 256 + tx * 4] = acc[n];
        float vs = 0.f, vd = 0.f;
        #pragma unroll
        for (int c = 0; c < 4; c++) { vs += acc[n][c] * asv[c]; vd += acc[n][c] * adv[c]; }
        // reduce within each 16-lane group (one head = lanes h*16..h*16+15, cols h*64..h*64+63)
        #pragma unroll
        for (int off = 8; off; off >>= 1) { vs += __shfl_down(vs, off); vd += __shfl_down(vd, off); }
        if ((tx & 15) == 0) {
            int h = tx >> 4;
            a_src1[node * 4 + h] = vs;
            a_dst1[node * 4 + h] = vd;
        }
    }
}

// ---------------- Layer 1 aggregation (segment softmax + weighted sum) ----------------
// one block (256 thr) per destination node; thread t = channel t, head = t>>6

__global__ __launch_bounds__(256) void agg1_kernel(
    const int* __restrict__ offsets, const int* __restrict__ csr_src,
    const float* __restrict__ a_src1, const float* __restrict__ a_dst1,
    const float* __restrict__ xh1, const float* __restrict__ b1,
    float* __restrict__ H)
{
    int n = blockIdx.x;
    int t = threadIdx.x;
    int h = t >> 6;
    int beg = offsets[n], end = offsets[n + 1];
    float adst = a_dst1[n * 4 + h];

    float m = -1e30f;
    for (int p = beg; p < end; p++) {
        int s = csr_src[p];
        float e = a_src1[s * 4 + h] + adst;
        e = e >= 0.f ? e : 0.2f * e;
        m = fmaxf(m, e);
    }
    float denom = 0.f, acc = 0.f;
    for (int p = beg; p < end; p++) {
        int s = csr_src[p];
        float e = a_src1[s * 4 + h] + adst;
        e = e >= 0.f ? e : 0.2f * e;
        float w = __expf(e - m);
        denom += w;
        acc += w * xh1[(size_t)s * 256 + t];
    }
    H[(size_t)n * 256 + t] = acc / denom + b1[t];
}

// ---------------- Layer 2 GEMM + attention dots ----------------
// xh2 = H@W2 [50000,256]@[256,128]; block 256: tx=t&31 (cols tx*4..+3), ty=t>>5 (nodes ty*2..+1)

__global__ __launch_bounds__(256) void gemm2_att_kernel(
    const float* __restrict__ H, const float* __restrict__ W2,
    const float* __restrict__ att_src, const float* __restrict__ att_dst,
    float* __restrict__ xh2, float* __restrict__ a_src2, float* __restrict__ a_dst2)
{
    __shared__ __align__(16) float Ws[64 * 128];   // 32 KB K-tile
    __shared__ __align__(16) float Hs[16 * 68];    // 16 nodes x 64 k, pad 68
    int t  = threadIdx.x;
    int tx = t & 31;
    int ty = t >> 5;
    int n0 = blockIdx.x * 16;

    v4 acc[2];
    acc[0] = (v4)0.f; acc[1] = (v4)0.f;

    for (int kt = 0; kt < 256; kt += 64) {
        __syncthreads();
        {
            const float4* Wv = (const float4*)(W2 + kt * 128);
            float4* Wsv = (float4*)Ws;
            for (int i = t; i < 2048; i += 256) Wsv[i] = Wv[i];
        }
        for (int i = t; i < 16 * 64; i += 256) {
            int r = i >> 6, c = i & 63;
            Hs[r * 68 + c] = H[(size_t)(n0 + r) * 256 + kt + c];
        }
        __syncthreads();
        #pragma unroll
        for (int k4 = 0; k4 < 16; k4++) {
            v4 hv[2], wv[4];
            #pragma unroll
            for (int n = 0; n < 2; n++) hv[n] = *(const v4*)&Hs[(ty * 2 + n) * 68 + k4 * 4];
            #pragma unroll
            for (int kk = 0; kk < 4; kk++) wv[kk] = *(const v4*)&Ws[(k4 * 4 + kk) * 128 + tx * 4];
            #pragma unroll
            for (int n = 0; n < 2; n++)
                #pragma unroll
                for (int kk = 0; kk < 4; kk++)
                    acc[n] += hv[n][kk] * wv[kk];
        }
    }

    v4 asv = *(const v4*)&att_src[tx * 4];  // [128]
    v4 adv = *(const v4*)&att_dst[tx * 4];
    #pragma unroll
    for (int n = 0; n < 2; n++) {
        int node = n0 + ty * 2 + n;
        *(v4*)&xh2[(size_t)node * 128 + tx * 4] = acc[n];
        float vs = 0.f, vd = 0.f;
        #pragma unroll
        for (int c = 0; c < 4; c++) { vs += acc[n][c] * asv[c]; vd += acc[n][c] * adv[c]; }
        // reduce over 32-lane half-wave (covers all 128 cols of this node)
        #pragma unroll
        for (int off = 16; off; off >>= 1) { vs += __shfl_down(vs, off); vd += __shfl_down(vd, off); }
        if ((t & 31) == 0) { a_src2[node] = vs; a_dst2[node] = vd; }
    }
}

// ---------------- Layer 2 aggregation ----------------
// one block (128 thr) per node, 1 head; writes final output (+bias)

__global__ __launch_bounds__(128) void agg2_kernel(
    const int* __restrict__ offsets, const int* __restrict__ csr_src,
    const float* __restrict__ a_src2, const float* __restrict__ a_dst2,
    const float* __restrict__ xh2, const float* __restrict__ b2,
    float* __restrict__ out)
{
    int n = blockIdx.x;
    int t = threadIdx.x;
    int beg = offsets[n], end = offsets[n + 1];
    float adst = a_dst2[n];

    float m = -1e30f;
    for (int p = beg; p < end; p++) {
        int s = csr_src[p];
        float e = a_src2[s] + adst;
        e = e >= 0.f ? e : 0.2f * e;
        m = fmaxf(m, e);
    }
    float denom = 0.f, acc = 0.f;
    for (int p = beg; p < end; p++) {
        int s = csr_src[p];
        float e = a_src2[s] + adst;
        e = e >= 0.f ? e : 0.2f * e;
        float w = __expf(e - m);
        denom += w;
        acc += w * xh2[(size_t)s * 128 + t];
    }
    out[(size_t)n * 128 + t] = acc / denom + b2[t];
}

// ---------------- launcher ----------------

extern "C" void kernel_launch(void* const* d_in, const int* in_sizes, int n_in,
                              void* d_out, int out_size, void* d_ws, size_t ws_size,
                              hipStream_t stream) {
    const float* X   = (const float*)d_in[0];
    const int*   ei  = (const int*)d_in[1];
    const float* W1  = (const float*)d_in[2];
    const float* as1 = (const float*)d_in[3];
    const float* ad1 = (const float*)d_in[4];
    const float* b1  = (const float*)d_in[5];
    const float* W2  = (const float*)d_in[6];
    const float* as2 = (const float*)d_in[7];
    const float* ad2 = (const float*)d_in[8];
    const float* b2  = (const float*)d_in[9];
    float* out = (float*)d_out;

    const int N = in_sizes[0] / 64;   // 50000
    const int E = in_sizes[1] / 2;    // 800000
    const int* srcArr = ei;
    const int* dstArr = ei + E;

    char* w = (char*)d_ws;
    float* xh1     = (float*)w;  w += (size_t)N * 256 * 4;
    float* Hbuf    = (float*)w;  w += (size_t)N * 256 * 4;
    float* a_src1  = (float*)w;  w += (size_t)N * 4 * 4;
    float* a_dst1  = (float*)w;  w += (size_t)N * 4 * 4;
    float* a_src2v = (float*)w;  w += (size_t)N * 4;
    float* a_dst2v = (float*)w;  w += (size_t)N * 4;
    int*   counts  = (int*)w;    w += (size_t)N * 4;
    int*   offsets = (int*)w;    w += (size_t)(N + 1) * 4;
    int*   cursor  = (int*)w;    w += (size_t)N * 4;
    int*   csr_src = (int*)w;    w += (size_t)(E + N) * 4;
    float* xh2 = xh1;  // xh1 is dead after agg1; reuse for layer-2 features

    init_kernel<<<(N + 255) / 256, 256, 0, stream>>>(counts, cursor, N);
    hist_kernel<<<(E + 255) / 256, 256, 0, stream>>>(dstArr, counts, E);
    scan_kernel<<<1, 1024, 0, stream>>>(counts, offsets, N);
    scatter_kernel<<<(E + N + 255) / 256, 256, 0, stream>>>(srcArr, dstArr, offsets, cursor,
                                                            csr_src, E, N);
    gemm1_att_kernel<<<N / 16, 256, 0, stream>>>(X, W1, as1, ad1, xh1, a_src1, a_dst1);
    agg1_kernel<<<N, 256, 0, stream>>>(offsets, csr_src, a_src1, a_dst1, xh1, b1, Hbuf);
    gemm2_att_kernel<<<N / 16, 256, 0, stream>>>(Hbuf, W2, as2, ad2, xh2, a_src2v, a_dst2v);
    agg2_kernel<<<N, 128, 0, stream>>>(offsets, csr_src, a_src2v, a_dst2v, xh2, b2, out);
}

// Round 2
// 624.855 us; speedup vs baseline: 1.3313x; 1.3313x over previous
//
#include <hip/hip_runtime.h>
#include <hip/hip_bf16.h>

typedef float v4 __attribute__((ext_vector_type(4)));
typedef float v2f __attribute__((ext_vector_type(2)));

// ---------------- CSR build (degree padded to multiple of 4) ----------------

__global__ __launch_bounds__(256) void init_kernel(int* counts, int* cursor, int N) {
    int i = blockIdx.x * 256 + threadIdx.x;
    if (i < N) { counts[i] = 1; /* self-loop */ cursor[i] = 0; }
}

__global__ __launch_bounds__(256) void hist_kernel(const int* __restrict__ dst, int* counts, int E) {
    int e = blockIdx.x * 256 + threadIdx.x;
    if (e < E) atomicAdd(&counts[dst[e]], 1);
}

// exclusive scan of padded degrees ((cnt+3)&~3); single block, chunked.
__global__ __launch_bounds__(1024) void scan_kernel(const int* __restrict__ counts,
                                                    int* __restrict__ offsets, int n) {
    __shared__ int partial[1024];
    int tid = threadIdx.x;
    int chunk = (n + 1023) / 1024;
    int b = tid * chunk;
    int e = b + chunk < n ? b + chunk : n;
    int s = 0;
    for (int i = b; i < e; i++) s += (counts[i] + 3) & ~3;
    partial[tid] = s;
    __syncthreads();
    for (int off = 1; off < 1024; off <<= 1) {
        int t2 = (tid >= off) ? partial[tid - off] : 0;
        __syncthreads();
        partial[tid] += t2;
        __syncthreads();
    }
    int run = partial[tid] - s;   // exclusive prefix of this chunk
    for (int i = b; i < e; i++) { offsets[i] = run; run += (counts[i] + 3) & ~3; }
    if (tid == 1023) offsets[n] = partial[1023];
}

__global__ __launch_bounds__(256) void scatter_kernel(const int* __restrict__ src,
                                                      const int* __restrict__ dst,
                                                      const int* __restrict__ offsets,
                                                      int* cursor, int* csr_src, int E, int N) {
    int id = blockIdx.x * 256 + threadIdx.x;
    if (id >= E + N) return;
    int d, s;
    if (id < E) { d = dst[id]; s = src[id]; }
    else        { d = id - E; s = d; }      // self-loop
    int pos = offsets[d] + atomicAdd(&cursor[d], 1);
    csr_src[pos] = s;
}

// ---------------- Layer 1 GEMM + attention dots ----------------

__global__ __launch_bounds__(256) void gemm1_att_kernel(
    const float* __restrict__ X, const float* __restrict__ W1,
    const float* __restrict__ att_src, const float* __restrict__ att_dst,
    float* __restrict__ xh1, float* __restrict__ a_src1, float* __restrict__ a_dst1)
{
    __shared__ __align__(16) float Ws[32 * 256];
    __shared__ __align__(16) float Xs[16 * 36];
    int t  = threadIdx.x;
    int tx = t & 63;
    int ty = t >> 6;
    int n0 = blockIdx.x * 16;

    v4 acc[4];
    #pragma unroll
    for (int n = 0; n < 4; n++) acc[n] = (v4)0.f;

    for (int kt = 0; kt < 64; kt += 32) {
        __syncthreads();
        {
            const float4* Wv = (const float4*)(W1 + kt * 256);
            float4* Wsv = (float4*)Ws;
            for (int i = t; i < 2048; i += 256) Wsv[i] = Wv[i];
        }
        for (int i = t; i < 16 * 32; i += 256) {
            int r = i >> 5, c = i & 31;
            Xs[r * 36 + c] = X[(size_t)(n0 + r) * 64 + kt + c];
        }
        __syncthreads();
        #pragma unroll
        for (int k4 = 0; k4 < 8; k4++) {
            v4 xv[4], wv[4];
            #pragma unroll
            for (int n = 0; n < 4; n++) xv[n] = *(const v4*)&Xs[(ty * 4 + n) * 36 + k4 * 4];
            #pragma unroll
            for (int kk = 0; kk < 4; kk++) wv[kk] = *(const v4*)&Ws[(k4 * 4 + kk) * 256 + tx * 4];
            #pragma unroll
            for (int n = 0; n < 4; n++)
                #pragma unroll
                for (int kk = 0; kk < 4; kk++)
                    acc[n] += xv[n][kk] * wv[kk];
        }
    }

    v4 asv = *(const v4*)&att_src[tx * 4];
    v4 adv = *(const v4*)&att_dst[tx * 4];
    #pragma unroll
    for (int n = 0; n < 4; n++) {
        int node = n0 + ty * 4 + n;
        *(v4*)&xh1[(size_t)node * 256 + tx * 4] = acc[n];
        float vs = 0.f, vd = 0.f;
        #pragma unroll
        for (int c = 0; c < 4; c++) { vs += acc[n][c] * asv[c]; vd += acc[n][c] * adv[c]; }
        #pragma unroll
        for (int off = 8; off; off >>= 1) { vs += __shfl_down(vs, off); vd += __shfl_down(vd, off); }
        if ((tx & 15) == 0) {
            int h = tx >> 4;
            a_src1[node * 4 + h] = vs;
            a_dst1[node * 4 + h] = vd;
        }
    }
}

// ---------------- Layer 1 softmax coefficients ----------------
// one wave per node; lanes parallel over edges; 4 heads per lane as float4.
// Also fills CSR pad slots (src=self, coeff=0).

__device__ __forceinline__ float leaky02(float x) { return x >= 0.f ? x : 0.2f * x; }

__global__ __launch_bounds__(256) void coeff1_kernel(
    const int* __restrict__ offsets, const int* __restrict__ counts,
    int* __restrict__ csr_src,
    const float* __restrict__ a_src1, const float* __restrict__ a_dst1,
    float* __restrict__ coeff)
{
    int wid  = threadIdx.x >> 6;
    int lane = threadIdx.x & 63;
    int n = blockIdx.x * 4 + wid;
    int beg = offsets[n];
    int cnt = counts[n];
    int degp = (cnt + 3) & ~3;
    v4 adst = *(const v4*)&a_dst1[n * 4];

    v4 m = (v4)(-1e30f);
    for (int q = lane; q < cnt; q += 64) {
        int s = csr_src[beg + q];
        v4 e = *(const v4*)&a_src1[s * 4];
        #pragma unroll
        for (int c = 0; c < 4; c++) { float x = e[c] + adst[c]; e[c] = leaky02(x); m[c] = fmaxf(m[c], e[c]); }
    }
    #pragma unroll
    for (int off = 32; off; off >>= 1)
        #pragma unroll
        for (int c = 0; c < 4; c++) m[c] = fmaxf(m[c], __shfl_xor(m[c], off));

    v4 den = (v4)0.f;
    if (cnt <= 64) {
        v4 ex = (v4)0.f;
        bool act = lane < cnt;
        if (act) {
            int s = csr_src[beg + lane];
            v4 e = *(const v4*)&a_src1[s * 4];
            #pragma unroll
            for (int c = 0; c < 4; c++) ex[c] = __expf(leaky02(e[c] + adst[c]) - m[c]);
            den = ex;
        }
        #pragma unroll
        for (int off = 32; off; off >>= 1)
            #pragma unroll
            for (int c = 0; c < 4; c++) den[c] += __shfl_xor(den[c], off);
        v4 inv;
        #pragma unroll
        for (int c = 0; c < 4; c++) inv[c] = 1.f / den[c];
        if (act) {
            v4 w; 
            #pragma unroll
            for (int c = 0; c < 4; c++) w[c] = ex[c] * inv[c];
            *(v4*)&coeff[(size_t)(beg + lane) * 4] = w;
        }
    } else {
        for (int q = lane; q < cnt; q += 64) {
            int s = csr_src[beg + q];
            v4 e = *(const v4*)&a_src1[s * 4], ex;
            #pragma unroll
            for (int c = 0; c < 4; c++) { ex[c] = __expf(leaky02(e[c] + adst[c]) - m[c]); den[c] += ex[c]; }
            *(v4*)&coeff[(size_t)(beg + q) * 4] = ex;
        }
        #pragma unroll
        for (int off = 32; off; off >>= 1)
            #pragma unroll
            for (int c = 0; c < 4; c++) den[c] += __shfl_xor(den[c], off);
        v4 inv;
        #pragma unroll
        for (int c = 0; c < 4; c++) inv[c] = 1.f / den[c];
        for (int q = lane; q < cnt; q += 64) {
            v4 w = *(const v4*)&coeff[(size_t)(beg + q) * 4];
            #pragma unroll
            for (int c = 0; c < 4; c++) w[c] *= inv[c];
            *(v4*)&coeff[(size_t)(beg + q) * 4] = w;
        }
    }
    // fill pads
    int q = cnt + lane;
    if (q < degp) {
        csr_src[beg + q] = n;
        *(v4*)&coeff[(size_t)(beg + q) * 4] = (v4)0.f;
    }
}

// ---------------- Layer 1 aggregation (pure weighted gather) ----------------
// one wave per node; lane l = channels 4l..4l+3 (float4); edges in chunks of 4,
// indices/weights pipelined one chunk ahead.

__global__ __launch_bounds__(256) void agg1b_kernel(
    const int* __restrict__ offsets, const int* __restrict__ csr_src,
    const float* __restrict__ coeff, const float* __restrict__ xh1,
    const float* __restrict__ b1, float* __restrict__ H)
{
    int wid  = threadIdx.x >> 6;
    int lane = threadIdx.x & 63;
    int n = blockIdx.x * 4 + wid;
    int beg  = offsets[n];
    int degp = offsets[n + 1] - beg;   // already multiple of 4
    int h  = lane >> 4;
    int c0 = lane * 4;

    v4 acc = (v4)0.f;
    int   sA[4]; float wA[4];
    #pragma unroll
    for (int k = 0; k < 4; k++) {
        int idx = beg + k;
        sA[k] = csr_src[idx];
        wA[k] = coeff[(size_t)idx * 4 + h];
    }
    for (int p = 0; p < degp; p += 4) {
        int pn = (p + 4 < degp) ? p + 4 : p;
        int sB[4]; float wB[4];
        #pragma unroll
        for (int k = 0; k < 4; k++) {
            int idx = beg + pn + k;
            sB[k] = csr_src[idx];
            wB[k] = coeff[(size_t)idx * 4 + h];
        }
        v4 x[4];
        #pragma unroll
        for (int k = 0; k < 4; k++) x[k] = *(const v4*)&xh1[(size_t)sA[k] * 256 + c0];
        #pragma unroll
        for (int k = 0; k < 4; k++) acc += wA[k] * x[k];
        #pragma unroll
        for (int k = 0; k < 4; k++) { sA[k] = sB[k]; wA[k] = wB[k]; }
    }
    v4 bias = *(const v4*)&b1[c0];
    *(v4*)&H[(size_t)n * 256 + c0] = acc + bias;
}

// ---------------- Layer 2 GEMM + attention dots ----------------

__global__ __launch_bounds__(256) void gemm2_att_kernel(
    const float* __restrict__ H, const float* __restrict__ W2,
    const float* __restrict__ att_src, const float* __restrict__ att_dst,
    float* __restrict__ xh2, float* __restrict__ a_src2, float* __restrict__ a_dst2)
{
    __shared__ __align__(16) float Ws[64 * 128];
    __shared__ __align__(16) float Hs[16 * 68];
    int t  = threadIdx.x;
    int tx = t & 31;
    int ty = t >> 5;
    int n0 = blockIdx.x * 16;

    v4 acc[2];
    acc[0] = (v4)0.f; acc[1] = (v4)0.f;

    for (int kt = 0; kt < 256; kt += 64) {
        __syncthreads();
        {
            const float4* Wv = (const float4*)(W2 + kt * 128);
            float4* Wsv = (float4*)Ws;
            for (int i = t; i < 2048; i += 256) Wsv[i] = Wv[i];
        }
        for (int i = t; i < 16 * 64; i += 256) {
            int r = i >> 6, c = i & 63;
            Hs[r * 68 + c] = H[(size_t)(n0 + r) * 256 + kt + c];
        }
        __syncthreads();
        #pragma unroll
        for (int k4 = 0; k4 < 16; k4++) {
            v4 hv[2], wv[4];
            #pragma unroll
            for (int n = 0; n < 2; n++) hv[n] = *(const v4*)&Hs[(ty * 2 + n) * 68 + k4 * 4];
            #pragma unroll
            for (int kk = 0; kk < 4; kk++) wv[kk] = *(const v4*)&Ws[(k4 * 4 + kk) * 128 + tx * 4];
            #pragma unroll
            for (int n = 0; n < 2; n++)
                #pragma unroll
                for (int kk = 0; kk < 4; kk++)
                    acc[n] += hv[n][kk] * wv[kk];
        }
    }

    v4 asv = *(const v4*)&att_src[tx * 4];
    v4 adv = *(const v4*)&att_dst[tx * 4];
    #pragma unroll
    for (int n = 0; n < 2; n++) {
        int node = n0 + ty * 2 + n;
        *(v4*)&xh2[(size_t)node * 128 + tx * 4] = acc[n];
        float vs = 0.f, vd = 0.f;
        #pragma unroll
        for (int c = 0; c < 4; c++) { vs += acc[n][c] * asv[c]; vd += acc[n][c] * adv[c]; }
        #pragma unroll
        for (int off = 16; off; off >>= 1) { vs += __shfl_down(vs, off); vd += __shfl_down(vd, off); }
        if ((t & 31) == 0) { a_src2[node] = vs; a_dst2[node] = vd; }
    }
}

// ---------------- Layer 2 softmax coefficients (1 head) ----------------

__global__ __launch_bounds__(256) void coeff2_kernel(
    const int* __restrict__ offsets, const int* __restrict__ counts,
    const int* __restrict__ csr_src,
    const float* __restrict__ a_src2, const float* __restrict__ a_dst2,
    float* __restrict__ coeff)
{
    int wid  = threadIdx.x >> 6;
    int lane = threadIdx.x & 63;
    int n = blockIdx.x * 4 + wid;
    int beg = offsets[n];
    int cnt = counts[n];
    int degp = (cnt + 3) & ~3;
    float adst = a_dst2[n];

    float m = -1e30f;
    for (int q = lane; q < cnt; q += 64) {
        int s = csr_src[beg + q];
        m = fmaxf(m, leaky02(a_src2[s] + adst));
    }
    #pragma unroll
    for (int off = 32; off; off >>= 1) m = fmaxf(m, __shfl_xor(m, off));

    float den = 0.f;
    if (cnt <= 64) {
        float ex = 0.f;
        bool act = lane < cnt;
        if (act) {
            int s = csr_src[beg + lane];
            ex = __expf(leaky02(a_src2[s] + adst) - m);
            den = ex;
        }
        #pragma unroll
        for (int off = 32; off; off >>= 1) den += __shfl_xor(den, off);
        float inv = 1.f / den;
        if (act) coeff[beg + lane] = ex * inv;
    } else {
        for (int q = lane; q < cnt; q += 64) {
            int s = csr_src[beg + q];
            float ex = __expf(leaky02(a_src2[s] + adst) - m);
            coeff[beg + q] = ex;
            den += ex;
        }
        #pragma unroll
        for (int off = 32; off; off >>= 1) den += __shfl_xor(den, off);
        float inv = 1.f / den;
        for (int q = lane; q < cnt; q += 64) coeff[beg + q] *= inv;
    }
    int q = cnt + lane;
    if (q < degp) coeff[beg + q] = 0.f;   // csr pad src already set by coeff1
}

// ---------------- Layer 2 aggregation ----------------
// one wave per node; lane l = channels 2l..2l+1 (float2)

__global__ __launch_bounds__(256) void agg2b_kernel(
    const int* __restrict__ offsets, const int* __restrict__ csr_src,
    const float* __restrict__ coeff, const float* __restrict__ xh2,
    const float* __restrict__ b2, float* __restrict__ out)
{
    int wid  = threadIdx.x >> 6;
    int lane = threadIdx.x & 63;
    int n = blockIdx.x * 4 + wid;
    int beg  = offsets[n];
    int degp = offsets[n + 1] - beg;
    int c0 = lane * 2;

    v2f acc = (v2f)0.f;
    int sA[4]; float wA[4];
    #pragma unroll
    for (int k = 0; k < 4; k++) {
        int idx = beg + k;
        sA[k] = csr_src[idx];
        wA[k] = coeff[idx];
    }
    for (int p = 0; p < degp; p += 4) {
        int pn = (p + 4 < degp) ? p + 4 : p;
        int sB[4]; float wB[4];
        #pragma unroll
        for (int k = 0; k < 4; k++) {
            int idx = beg + pn + k;
            sB[k] = csr_src[idx];
            wB[k] = coeff[idx];
        }
        v2f x[4];
        #pragma unroll
        for (int k = 0; k < 4; k++) x[k] = *(const v2f*)&xh2[(size_t)sA[k] * 128 + c0];
        #pragma unroll
        for (int k = 0; k < 4; k++) acc += wA[k] * x[k];
        #pragma unroll
        for (int k = 0; k < 4; k++) { sA[k] = sB[k]; wA[k] = wB[k]; }
    }
    v2f bias = *(const v2f*)&b2[c0];
    *(v2f*)&out[(size_t)n * 128 + c0] = acc + bias;
}

// ---------------- launcher ----------------

static inline size_t rnd256(size_t x) { return (x + 255) & ~(size_t)255; }

extern "C" void kernel_launch(void* const* d_in, const int* in_sizes, int n_in,
                              void* d_out, int out_size, void* d_ws, size_t ws_size,
                              hipStream_t stream) {
    const float* X   = (const float*)d_in[0];
    const int*   ei  = (const int*)d_in[1];
    const float* W1  = (const float*)d_in[2];
    const float* as1 = (const float*)d_in[3];
    const float* ad1 = (const float*)d_in[4];
    const float* b1  = (const float*)d_in[5];
    const float* W2  = (const float*)d_in[6];
    const float* as2 = (const float*)d_in[7];
    const float* ad2 = (const float*)d_in[8];
    const float* b2  = (const float*)d_in[9];
    float* out = (float*)d_out;

    const int N = in_sizes[0] / 64;   // 50000
    const int E = in_sizes[1] / 2;    // 800000
    const int* srcArr = ei;
    const int* dstArr = ei + E;
    const size_t CSRMAX = (size_t)E + 4 * (size_t)N;  // padded capacity

    char* w = (char*)d_ws;
    float* xh1     = (float*)w;  w += rnd256((size_t)N * 256 * 4);
    float* Hbuf    = (float*)w;  w += rnd256((size_t)N * 256 * 4);
    float* a_src1  = (float*)w;  w += rnd256((size_t)N * 4 * 4);
    float* a_dst1  = (float*)w;  w += rnd256((size_t)N * 4 * 4);
    float* a_src2v = (float*)w;  w += rnd256((size_t)N * 4);
    float* a_dst2v = (float*)w;  w += rnd256((size_t)N * 4);
    int*   counts  = (int*)w;    w += rnd256((size_t)N * 4);
    int*   offsets = (int*)w;    w += rnd256((size_t)(N + 1) * 4);
    int*   cursor  = (int*)w;    w += rnd256((size_t)N * 4);
    int*   csr_src = (int*)w;    w += rnd256(CSRMAX * 4);
    float* coeffA  = (float*)w;  w += rnd256(CSRMAX * 4 * 4);
    float* xh2     = xh1;        // xh1 dead after agg1b
    float* coeffB  = coeffA;     // coeffA dead after agg1b

    init_kernel<<<(N + 255) / 256, 256, 0, stream>>>(counts, cursor, N);
    hist_kernel<<<(E + 255) / 256, 256, 0, stream>>>(dstArr, counts, E);
    scan_kernel<<<1, 1024, 0, stream>>>(counts, offsets, N);
    scatter_kernel<<<(E + N + 255) / 256, 256, 0, stream>>>(srcArr, dstArr, offsets, cursor,
                                                            csr_src, E, N);
    gemm1_att_kernel<<<N / 16, 256, 0, stream>>>(X, W1, as1, ad1, xh1, a_src1, a_dst1);
    coeff1_kernel<<<N / 4, 256, 0, stream>>>(offsets, counts, csr_src, a_src1, a_dst1, coeffA);
    agg1b_kernel<<<N / 4, 256, 0, stream>>>(offsets, csr_src, coeffA, xh1, b1, Hbuf);
    gemm2_att_kernel<<<N / 16, 256, 0, stream>>>(Hbuf, W2, as2, ad2, xh2, a_src2v, a_dst2v);
    coeff2_kernel<<<N / 4, 256, 0, stream>>>(offsets, counts, csr_src, a_src2v, a_dst2v, coeffB);
    agg2b_kernel<<<N / 4, 256, 0, stream>>>(offsets, csr_src, coeffB, xh2, b2, out);
}

// Round 3
// 466.724 us; speedup vs baseline: 1.7824x; 1.3388x over previous
//
#include <hip/hip_runtime.h>
#include <hip/hip_bf16.h>

typedef float v4 __attribute__((ext_vector_type(4)));

__device__ __forceinline__ unsigned short f2bf(float f) {   // RNE fp32->bf16
    unsigned u = __float_as_uint(f);
    unsigned r = (u + 0x7fffu + ((u >> 16) & 1u)) >> 16;
    return (unsigned short)r;
}
__device__ __forceinline__ v4 bf4tof(ushort4 u) {
    v4 r;
    r[0] = __uint_as_float(((unsigned)u.x) << 16);
    r[1] = __uint_as_float(((unsigned)u.y) << 16);
    r[2] = __uint_as_float(((unsigned)u.z) << 16);
    r[3] = __uint_as_float(((unsigned)u.w) << 16);
    return r;
}
__device__ __forceinline__ float leaky02(float x) { return x >= 0.f ? x : 0.2f * x; }

// ---------------- CSR build (degree padded to multiple of 8) ----------------

__global__ __launch_bounds__(256) void init_kernel(int* counts, int* cursor, int N) {
    int i = blockIdx.x * 256 + threadIdx.x;
    if (i < N) { counts[i] = 1; /* self-loop */ cursor[i] = 0; }
}

__global__ __launch_bounds__(256) void hist_kernel(const int* __restrict__ dst, int* counts, int E) {
    int e = blockIdx.x * 256 + threadIdx.x;
    if (e < E) atomicAdd(&counts[dst[e]], 1);
}

// decoupled 3-phase scan of padded degrees ((cnt+7)&~7), 1024 elems/block
__global__ __launch_bounds__(256) void scanA_kernel(const int* __restrict__ counts,
                                                    int* __restrict__ blockSums, int n) {
    __shared__ int red[256];
    int b = blockIdx.x, t = threadIdx.x;
    int base = b * 1024;
    int s = 0;
    #pragma unroll
    for (int j = 0; j < 4; j++) {
        int i = base + j * 256 + t;
        if (i < n) s += (counts[i] + 7) & ~7;
    }
    red[t] = s; __syncthreads();
    for (int off = 128; off; off >>= 1) { if (t < off) red[t] += red[t + off]; __syncthreads(); }
    if (t == 0) blockSums[b] = red[0];
}

__global__ void scanB_kernel(const int* __restrict__ blockSums, int* __restrict__ blockBase,
                             int nb, int* __restrict__ offsets, int n) {
    int t = threadIdx.x;               // one wave, nb <= 64
    int orig = (t < nb) ? blockSums[t] : 0;
    int v = orig;
    #pragma unroll
    for (int off = 1; off < 64; off <<= 1) {
        int u = __shfl_up(v, off);
        if (t >= off) v += u;
    }
    if (t < nb) blockBase[t] = v - orig;
    if (t == nb - 1) offsets[n] = v;
}

__global__ __launch_bounds__(256) void scanC_kernel(const int* __restrict__ counts,
                                                    const int* __restrict__ blockBase,
                                                    int* __restrict__ offsets, int n) {
    __shared__ int red[256];
    int b = blockIdx.x, t = threadIdx.x;
    int base = b * 1024;
    int c[4]; int s = 0;
    #pragma unroll
    for (int j = 0; j < 4; j++) {
        int i = base + t * 4 + j;
        c[j] = (i < n) ? ((counts[i] + 7) & ~7) : 0;
        s += c[j];
    }
    red[t] = s; __syncthreads();
    for (int off = 1; off < 256; off <<= 1) {
        int u = (t >= off) ? red[t - off] : 0;
        __syncthreads();
        red[t] += u;
        __syncthreads();
    }
    int excl = red[t] - s + blockBase[b];
    #pragma unroll
    for (int j = 0; j < 4; j++) {
        int i = base + t * 4 + j;
        if (i < n) offsets[i] = excl;
        excl += c[j];
    }
}

__global__ __launch_bounds__(256) void scatter_kernel(const int* __restrict__ src,
                                                      const int* __restrict__ dst,
                                                      const int* __restrict__ offsets,
                                                      int* cursor, int* csr_src, int E, int N) {
    int id = blockIdx.x * 256 + threadIdx.x;
    if (id >= E + N) return;
    int d, s;
    if (id < E) { d = dst[id]; s = src[id]; }
    else        { d = id - E; s = d; }      // self-loop
    int pos = offsets[d] + atomicAdd(&cursor[d], 1);
    csr_src[pos] = s;
}

// ---------------- Layer 1 GEMM + attention dots (bf16 feature output) ----------------

__global__ __launch_bounds__(256) void gemm1_att_kernel(
    const float* __restrict__ X, const float* __restrict__ W1,
    const float* __restrict__ att_src, const float* __restrict__ att_dst,
    unsigned short* __restrict__ xh1_bf, float* __restrict__ a_src1, float* __restrict__ a_dst1)
{
    __shared__ __align__(16) float Ws[32 * 256];
    __shared__ __align__(16) float Xs[16 * 36];
    int t  = threadIdx.x;
    int tx = t & 63;
    int ty = t >> 6;
    int n0 = blockIdx.x * 16;

    v4 acc[4];
    #pragma unroll
    for (int n = 0; n < 4; n++) acc[n] = (v4)0.f;

    for (int kt = 0; kt < 64; kt += 32) {
        __syncthreads();
        {
            const float4* Wv = (const float4*)(W1 + kt * 256);
            float4* Wsv = (float4*)Ws;
            for (int i = t; i < 2048; i += 256) Wsv[i] = Wv[i];
        }
        for (int i = t; i < 16 * 32; i += 256) {
            int r = i >> 5, c = i & 31;
            Xs[r * 36 + c] = X[(size_t)(n0 + r) * 64 + kt + c];
        }
        __syncthreads();
        #pragma unroll
        for (int k4 = 0; k4 < 8; k4++) {
            v4 xv[4], wv[4];
            #pragma unroll
            for (int n = 0; n < 4; n++) xv[n] = *(const v4*)&Xs[(ty * 4 + n) * 36 + k4 * 4];
            #pragma unroll
            for (int kk = 0; kk < 4; kk++) wv[kk] = *(const v4*)&Ws[(k4 * 4 + kk) * 256 + tx * 4];
            #pragma unroll
            for (int n = 0; n < 4; n++)
                #pragma unroll
                for (int kk = 0; kk < 4; kk++)
                    acc[n] += xv[n][kk] * wv[kk];
        }
    }

    v4 asv = *(const v4*)&att_src[tx * 4];
    v4 adv = *(const v4*)&att_dst[tx * 4];
    #pragma unroll
    for (int n = 0; n < 4; n++) {
        int node = n0 + ty * 4 + n;
        ushort4 bfv;
        bfv.x = f2bf(acc[n][0]); bfv.y = f2bf(acc[n][1]);
        bfv.z = f2bf(acc[n][2]); bfv.w = f2bf(acc[n][3]);
        *(ushort4*)&xh1_bf[(size_t)node * 256 + tx * 4] = bfv;
        float vs = 0.f, vd = 0.f;
        #pragma unroll
        for (int c = 0; c < 4; c++) { vs += acc[n][c] * asv[c]; vd += acc[n][c] * adv[c]; }
        #pragma unroll
        for (int off = 8; off; off >>= 1) { vs += __shfl_down(vs, off); vd += __shfl_down(vd, off); }
        if ((tx & 15) == 0) {
            int h = tx >> 4;
            a_src1[node * 4 + h] = vs;
            a_dst1[node * 4 + h] = vd;
        }
    }
}

// ---------------- Layer 1 softmax coefficients ----------------

__global__ __launch_bounds__(256) void coeff1_kernel(
    const int* __restrict__ offsets, const int* __restrict__ counts,
    int* __restrict__ csr_src,
    const float* __restrict__ a_src1, const float* __restrict__ a_dst1,
    float* __restrict__ coeff)
{
    int wid  = threadIdx.x >> 6;
    int lane = threadIdx.x & 63;
    int n = blockIdx.x * 4 + wid;
    int beg = offsets[n];
    int cnt = counts[n];
    int degp = (cnt + 7) & ~7;
    v4 adst = *(const v4*)&a_dst1[n * 4];

    v4 m = (v4)(-1e30f);
    for (int q = lane; q < cnt; q += 64) {
        int s = csr_src[beg + q];
        v4 e = *(const v4*)&a_src1[s * 4];
        #pragma unroll
        for (int c = 0; c < 4; c++) { float x = e[c] + adst[c]; e[c] = leaky02(x); m[c] = fmaxf(m[c], e[c]); }
    }
    #pragma unroll
    for (int off = 32; off; off >>= 1)
        #pragma unroll
        for (int c = 0; c < 4; c++) m[c] = fmaxf(m[c], __shfl_xor(m[c], off));

    v4 den = (v4)0.f;
    if (cnt <= 64) {
        v4 ex = (v4)0.f;
        bool act = lane < cnt;
        if (act) {
            int s = csr_src[beg + lane];
            v4 e = *(const v4*)&a_src1[s * 4];
            #pragma unroll
            for (int c = 0; c < 4; c++) ex[c] = __expf(leaky02(e[c] + adst[c]) - m[c]);
            den = ex;
        }
        #pragma unroll
        for (int off = 32; off; off >>= 1)
            #pragma unroll
            for (int c = 0; c < 4; c++) den[c] += __shfl_xor(den[c], off);
        v4 inv;
        #pragma unroll
        for (int c = 0; c < 4; c++) inv[c] = 1.f / den[c];
        if (act) {
            v4 w;
            #pragma unroll
            for (int c = 0; c < 4; c++) w[c] = ex[c] * inv[c];
            *(v4*)&coeff[(size_t)(beg + lane) * 4] = w;
        }
    } else {
        for (int q = lane; q < cnt; q += 64) {
            int s = csr_src[beg + q];
            v4 e = *(const v4*)&a_src1[s * 4], ex;
            #pragma unroll
            for (int c = 0; c < 4; c++) { ex[c] = __expf(leaky02(e[c] + adst[c]) - m[c]); den[c] += ex[c]; }
            *(v4*)&coeff[(size_t)(beg + q) * 4] = ex;
        }
        #pragma unroll
        for (int off = 32; off; off >>= 1)
            #pragma unroll
            for (int c = 0; c < 4; c++) den[c] += __shfl_xor(den[c], off);
        v4 inv;
        #pragma unroll
        for (int c = 0; c < 4; c++) inv[c] = 1.f / den[c];
        for (int q = lane; q < cnt; q += 64) {
            v4 w = *(const v4*)&coeff[(size_t)(beg + q) * 4];
            #pragma unroll
            for (int c = 0; c < 4; c++) w[c] *= inv[c];
            *(v4*)&coeff[(size_t)(beg + q) * 4] = w;
        }
    }
    int q = cnt + lane;
    if (q < degp) {
        csr_src[beg + q] = n;
        *(v4*)&coeff[(size_t)(beg + q) * 4] = (v4)0.f;
    }
}

// ---------------- Layer 1 aggregation: bf16 gather, 3-stage pipeline ----------------
// one wave per node; lane covers channels 4l..4l+3 (bf16x4 = 8B loads);
// chunks of 4 edges; idx/coeff prefetched 2 chunks ahead, features 1 ahead.

__global__ __launch_bounds__(256) void agg1b_kernel(
    const int* __restrict__ offsets, const int* __restrict__ csr_src,
    const float* __restrict__ coeff, const unsigned short* __restrict__ xh,
    const float* __restrict__ b1, float* __restrict__ H)
{
    int wid  = threadIdx.x >> 6;
    int lane = threadIdx.x & 63;
    int n = blockIdx.x * 4 + wid;
    int beg   = offsets[n];
    int steps = (offsets[n + 1] - beg) >> 2;   // degp multiple of 8 => >=2 chunks of 4
    int h  = lane >> 4;
    int c0 = lane * 4;

    v4 acc = (v4)0.f;
    int s0[4], s1[4], s2[4]; float w0[4], w1[4], w2[4];
    ushort4 x0[4], x1[4];

    #pragma unroll
    for (int k = 0; k < 4; k++) {
        int idx = beg + k;
        s0[k] = csr_src[idx]; w0[k] = coeff[idx * 4 + h];
    }
    {
        int c1 = (1 < steps) ? 1 : 0;
        #pragma unroll
        for (int k = 0; k < 4; k++) {
            int idx = beg + c1 * 4 + k;
            s1[k] = csr_src[idx]; w1[k] = coeff[idx * 4 + h];
        }
    }
    #pragma unroll
    for (int k = 0; k < 4; k++) x0[k] = *(const ushort4*)&xh[(size_t)s0[k] * 256 + c0];

    for (int i = 0; i < steps; i++) {
        int i2 = (i + 2 < steps) ? i + 2 : steps - 1;
        #pragma unroll
        for (int k = 0; k < 4; k++) {
            int idx = beg + i2 * 4 + k;
            s2[k] = csr_src[idx]; w2[k] = coeff[idx * 4 + h];
        }
        if (i + 1 < steps) {
            #pragma unroll
            for (int k = 0; k < 4; k++) x1[k] = *(const ushort4*)&xh[(size_t)s1[k] * 256 + c0];
        }
        #pragma unroll
        for (int k = 0; k < 4; k++) acc += w0[k] * bf4tof(x0[k]);
        #pragma unroll
        for (int k = 0; k < 4; k++) {
            x0[k] = x1[k]; w0[k] = w1[k];
            s1[k] = s2[k]; w1[k] = w2[k];
        }
    }
    v4 bias = *(const v4*)&b1[c0];
    *(v4*)&H[(size_t)n * 256 + c0] = acc + bias;
}

// ---------------- Layer 2 GEMM + attention dots (4 rows/thread, bf16 out) ----------------

__global__ __launch_bounds__(256) void gemm2_att_kernel(
    const float* __restrict__ H, const float* __restrict__ W2,
    const float* __restrict__ att_src, const float* __restrict__ att_dst,
    unsigned short* __restrict__ xh2_bf, float* __restrict__ a_src2, float* __restrict__ a_dst2,
    int N)
{
    __shared__ __align__(16) float Ws[64 * 128];   // 32 KB
    __shared__ __align__(16) float Hs[32 * 68];    // 8.7 KB
    int t  = threadIdx.x;
    int tx = t & 31;
    int ty = t >> 5;                 // 8 row groups x 4 rows = 32 rows/block
    int n0 = blockIdx.x * 32;

    v4 acc[4];
    #pragma unroll
    for (int n = 0; n < 4; n++) acc[n] = (v4)0.f;

    for (int kt = 0; kt < 256; kt += 64) {
        __syncthreads();
        {
            const float4* Wv = (const float4*)(W2 + kt * 128);
            float4* Wsv = (float4*)Ws;
            for (int i = t; i < 2048; i += 256) Wsv[i] = Wv[i];
        }
        for (int i = t; i < 32 * 64; i += 256) {
            int r = i >> 6, c = i & 63;
            int row = n0 + r; if (row >= N) row = N - 1;
            Hs[r * 68 + c] = H[(size_t)row * 256 + kt + c];
        }
        __syncthreads();
        #pragma unroll
        for (int k4 = 0; k4 < 16; k4++) {
            v4 hv[4], wv[4];
            #pragma unroll
            for (int n = 0; n < 4; n++) hv[n] = *(const v4*)&Hs[(ty * 4 + n) * 68 + k4 * 4];
            #pragma unroll
            for (int kk = 0; kk < 4; kk++) wv[kk] = *(const v4*)&Ws[(k4 * 4 + kk) * 128 + tx * 4];
            #pragma unroll
            for (int n = 0; n < 4; n++)
                #pragma unroll
                for (int kk = 0; kk < 4; kk++)
                    acc[n] += hv[n][kk] * wv[kk];
        }
    }

    v4 asv = *(const v4*)&att_src[tx * 4];
    v4 adv = *(const v4*)&att_dst[tx * 4];
    #pragma unroll
    for (int n = 0; n < 4; n++) {
        int node = n0 + ty * 4 + n;
        float vs = 0.f, vd = 0.f;
        #pragma unroll
        for (int c = 0; c < 4; c++) { vs += acc[n][c] * asv[c]; vd += acc[n][c] * adv[c]; }
        #pragma unroll
        for (int off = 16; off; off >>= 1) { vs += __shfl_down(vs, off); vd += __shfl_down(vd, off); }
        if (node < N) {
            ushort4 bfv;
            bfv.x = f2bf(acc[n][0]); bfv.y = f2bf(acc[n][1]);
            bfv.z = f2bf(acc[n][2]); bfv.w = f2bf(acc[n][3]);
            *(ushort4*)&xh2_bf[(size_t)node * 128 + tx * 4] = bfv;
            if ((t & 31) == 0) { a_src2[node] = vs; a_dst2[node] = vd; }
        }
    }
}

// ---------------- Layer 2 softmax coefficients (1 head) ----------------

__global__ __launch_bounds__(256) void coeff2_kernel(
    const int* __restrict__ offsets, const int* __restrict__ counts,
    const int* __restrict__ csr_src,
    const float* __restrict__ a_src2, const float* __restrict__ a_dst2,
    float* __restrict__ coeff)
{
    int wid  = threadIdx.x >> 6;
    int lane = threadIdx.x & 63;
    int n = blockIdx.x * 4 + wid;
    int beg = offsets[n];
    int cnt = counts[n];
    int degp = (cnt + 7) & ~7;
    float adst = a_dst2[n];

    float m = -1e30f;
    for (int q = lane; q < cnt; q += 64) {
        int s = csr_src[beg + q];
        m = fmaxf(m, leaky02(a_src2[s] + adst));
    }
    #pragma unroll
    for (int off = 32; off; off >>= 1) m = fmaxf(m, __shfl_xor(m, off));

    float den = 0.f;
    if (cnt <= 64) {
        float ex = 0.f;
        bool act = lane < cnt;
        if (act) {
            int s = csr_src[beg + lane];
            ex = __expf(leaky02(a_src2[s] + adst) - m);
            den = ex;
        }
        #pragma unroll
        for (int off = 32; off; off >>= 1) den += __shfl_xor(den, off);
        float inv = 1.f / den;
        if (act) coeff[beg + lane] = ex * inv;
    } else {
        for (int q = lane; q < cnt; q += 64) {
            int s = csr_src[beg + q];
            float ex = __expf(leaky02(a_src2[s] + adst) - m);
            coeff[beg + q] = ex;
            den += ex;
        }
        #pragma unroll
        for (int off = 32; off; off >>= 1) den += __shfl_xor(den, off);
        float inv = 1.f / den;
        for (int q = lane; q < cnt; q += 64) coeff[beg + q] *= inv;
    }
    int q = cnt + lane;
    if (q < degp) coeff[beg + q] = 0.f;
}

// ---------------- Layer 2 aggregation: bf16 gather, 2 edges/load, pipelined ----------------
// one wave per node; half-wave hh handles edge (i*8 + 2k + hh); lane covers
// channels (lane&31)*4 (bf16x4 = 8B); chunks of 8 edges; final shfl_xor(32) combine.

__global__ __launch_bounds__(256) void agg2b_kernel(
    const int* __restrict__ offsets, const int* __restrict__ csr_src,
    const float* __restrict__ coeff, const unsigned short* __restrict__ xh2,
    const float* __restrict__ b2, float* __restrict__ out)
{
    int wid  = threadIdx.x >> 6;
    int lane = threadIdx.x & 63;
    int n = blockIdx.x * 4 + wid;
    int beg   = offsets[n];
    int steps = (offsets[n + 1] - beg) >> 3;   // chunks of 8 edges
    int hh = lane >> 5;
    int c0 = (lane & 31) * 4;

    v4 acc = (v4)0.f;
    int s0[4], s1[4], s2[4]; float w0[4], w1[4], w2[4];
    ushort4 x0[4], x1[4];

    #pragma unroll
    for (int k = 0; k < 4; k++) {
        int idx = beg + 2 * k + hh;
        s0[k] = csr_src[idx]; w0[k] = coeff[idx];
    }
    {
        int c1 = (1 < steps) ? 1 : 0;
        #pragma unroll
        for (int k = 0; k < 4; k++) {
            int idx = beg + c1 * 8 + 2 * k + hh;
            s1[k] = csr_src[idx]; w1[k] = coeff[idx];
        }
    }
    #pragma unroll
    for (int k = 0; k < 4; k++) x0[k] = *(const ushort4*)&xh2[(size_t)s0[k] * 128 + c0];

    for (int i = 0; i < steps; i++) {
        int i2 = (i + 2 < steps) ? i + 2 : steps - 1;
        #pragma unroll
        for (int k = 0; k < 4; k++) {
            int idx = beg + i2 * 8 + 2 * k + hh;
            s2[k] = csr_src[idx]; w2[k] = coeff[idx];
        }
        if (i + 1 < steps) {
            #pragma unroll
            for (int k = 0; k < 4; k++) x1[k] = *(const ushort4*)&xh2[(size_t)s1[k] * 128 + c0];
        }
        #pragma unroll
        for (int k = 0; k < 4; k++) acc += w0[k] * bf4tof(x0[k]);
        #pragma unroll
        for (int k = 0; k < 4; k++) {
            x0[k] = x1[k]; w0[k] = w1[k];
            s1[k] = s2[k]; w1[k] = w2[k];
        }
    }
    #pragma unroll
    for (int c = 0; c < 4; c++) acc[c] += __shfl_xor(acc[c], 32);
    if (lane < 32) {
        v4 bias = *(const v4*)&b2[c0];
        *(v4*)&out[(size_t)n * 128 + c0] = acc + bias;
    }
}

// ---------------- launcher ----------------

static inline size_t rnd256(size_t x) { return (x + 255) & ~(size_t)255; }

extern "C" void kernel_launch(void* const* d_in, const int* in_sizes, int n_in,
                              void* d_out, int out_size, void* d_ws, size_t ws_size,
                              hipStream_t stream) {
    const float* X   = (const float*)d_in[0];
    const int*   ei  = (const int*)d_in[1];
    const float* W1  = (const float*)d_in[2];
    const float* as1 = (const float*)d_in[3];
    const float* ad1 = (const float*)d_in[4];
    const float* b1  = (const float*)d_in[5];
    const float* W2  = (const float*)d_in[6];
    const float* as2 = (const float*)d_in[7];
    const float* ad2 = (const float*)d_in[8];
    const float* b2  = (const float*)d_in[9];
    float* out = (float*)d_out;

    const int N = in_sizes[0] / 64;   // 50000
    const int E = in_sizes[1] / 2;    // 800000
    const int* srcArr = ei;
    const int* dstArr = ei + E;
    const size_t CSRMAX = (size_t)E + 8 * (size_t)N;  // padded capacity
    const int NB = (N + 1023) / 1024;

    char* w = (char*)d_ws;
    unsigned short* xh1_bf = (unsigned short*)w;  w += rnd256((size_t)N * 256 * 2);
    float* Hbuf    = (float*)w;  w += rnd256((size_t)(N + 32) * 256 * 4);
    float* a_src1  = (float*)w;  w += rnd256((size_t)N * 4 * 4);
    float* a_dst1  = (float*)w;  w += rnd256((size_t)N * 4 * 4);
    float* a_src2v = (float*)w;  w += rnd256((size_t)N * 4);
    float* a_dst2v = (float*)w;  w += rnd256((size_t)N * 4);
    int*   counts  = (int*)w;    w += rnd256((size_t)N * 4);
    int*   offsets = (int*)w;    w += rnd256((size_t)(N + 1) * 4);
    int*   cursor  = (int*)w;    w += rnd256((size_t)N * 4);
    int*   blockSums = (int*)w;  w += rnd256((size_t)NB * 4);
    int*   blockBase = (int*)w;  w += rnd256((size_t)NB * 4);
    int*   csr_src = (int*)w;    w += rnd256(CSRMAX * 4);
    float* coeffA  = (float*)w;  w += rnd256(CSRMAX * 4 * 4);
    unsigned short* xh2_bf = xh1_bf;  // dead after agg1b
    float* coeffB  = coeffA;          // dead after agg1b

    init_kernel<<<(N + 255) / 256, 256, 0, stream>>>(counts, cursor, N);
    hist_kernel<<<(E + 255) / 256, 256, 0, stream>>>(dstArr, counts, E);
    scanA_kernel<<<NB, 256, 0, stream>>>(counts, blockSums, N);
    scanB_kernel<<<1, 64, 0, stream>>>(blockSums, blockBase, NB, offsets, N);
    scanC_kernel<<<NB, 256, 0, stream>>>(counts, blockBase, offsets, N);
    scatter_kernel<<<(E + N + 255) / 256, 256, 0, stream>>>(srcArr, dstArr, offsets, cursor,
                                                            csr_src, E, N);
    gemm1_att_kernel<<<N / 16, 256, 0, stream>>>(X, W1, as1, ad1, xh1_bf, a_src1, a_dst1);
    coeff1_kernel<<<N / 4, 256, 0, stream>>>(offsets, counts, csr_src, a_src1, a_dst1, coeffA);
    agg1b_kernel<<<N / 4, 256, 0, stream>>>(offsets, csr_src, coeffA, xh1_bf, b1, Hbuf);
    gemm2_att_kernel<<<(N + 31) / 32, 256, 0, stream>>>(Hbuf, W2, as2, ad2, xh2_bf,
                                                        a_src2v, a_dst2v, N);
    coeff2_kernel<<<N / 4, 256, 0, stream>>>(offsets, counts, csr_src, a_src2v, a_dst2v, coeffB);
    agg2b_kernel<<<N / 4, 256, 0, stream>>>(offsets, csr_src, coeffB, xh2_bf, b2, out);
}

// Round 4
// 371.461 us; speedup vs baseline: 2.2395x; 1.2565x over previous
//
#include <hip/hip_runtime.h>
#include <hip/hip_bf16.h>

typedef float v4 __attribute__((ext_vector_type(4)));
typedef short bf8 __attribute__((ext_vector_type(8)));

__device__ __forceinline__ unsigned short f2bf(float f) {   // RNE fp32->bf16
    unsigned u = __float_as_uint(f);
    unsigned r = (u + 0x7fffu + ((u >> 16) & 1u)) >> 16;
    return (unsigned short)r;
}
__device__ __forceinline__ v4 bf4tof(ushort4 u) {
    v4 r;
    r[0] = __uint_as_float(((unsigned)u.x) << 16);
    r[1] = __uint_as_float(((unsigned)u.y) << 16);
    r[2] = __uint_as_float(((unsigned)u.z) << 16);
    r[3] = __uint_as_float(((unsigned)u.w) << 16);
    return r;
}
__device__ __forceinline__ float leaky02(float x) { return x >= 0.f ? x : 0.2f * x; }

// ---------------- precision prep: X -> bf16, W -> transposed bf16 ----------------

__global__ __launch_bounds__(256) void convX_kernel(const float* __restrict__ X,
                                                    unsigned short* __restrict__ Xbf, int total) {
    int i = (blockIdx.x * 256 + threadIdx.x) * 8;
    if (i >= total) return;
    float4 a = *(const float4*)&X[i];
    float4 b = *(const float4*)&X[i + 4];
    ushort4 r0; r0.x = f2bf(a.x); r0.y = f2bf(a.y); r0.z = f2bf(a.z); r0.w = f2bf(a.w);
    ushort4 r1; r1.x = f2bf(b.x); r1.y = f2bf(b.y); r1.z = f2bf(b.z); r1.w = f2bf(b.w);
    *(ushort4*)&Xbf[i] = r0;
    *(ushort4*)&Xbf[i + 4] = r1;
}

// W [K][Ncol] -> WT_bf [Ncol][K]
__global__ __launch_bounds__(256) void convWT_kernel(const float* __restrict__ W,
                                                     unsigned short* __restrict__ WT,
                                                     int K, int Ncol) {
    int id = blockIdx.x * 256 + threadIdx.x;
    if (id >= K * Ncol) return;
    int j = id / K, k = id - j * K;
    WT[id] = f2bf(W[k * Ncol + j]);
}

// ---------------- CSR build (degree padded to multiple of 8) ----------------

__global__ __launch_bounds__(256) void init_kernel(int* counts, int* cursor, int N) {
    int i = blockIdx.x * 256 + threadIdx.x;
    if (i < N) { counts[i] = 1; /* self-loop */ cursor[i] = 0; }
}

__global__ __launch_bounds__(256) void hist_kernel(const int* __restrict__ dst, int* counts, int E) {
    int e = blockIdx.x * 256 + threadIdx.x;
    if (e < E) atomicAdd(&counts[dst[e]], 1);
}

__global__ __launch_bounds__(256) void scanA_kernel(const int* __restrict__ counts,
                                                    int* __restrict__ blockSums, int n) {
    __shared__ int red[256];
    int b = blockIdx.x, t = threadIdx.x;
    int base = b * 1024;
    int s = 0;
    #pragma unroll
    for (int j = 0; j < 4; j++) {
        int i = base + j * 256 + t;
        if (i < n) s += (counts[i] + 7) & ~7;
    }
    red[t] = s; __syncthreads();
    for (int off = 128; off; off >>= 1) { if (t < off) red[t] += red[t + off]; __syncthreads(); }
    if (t == 0) blockSums[b] = red[0];
}

__global__ void scanB_kernel(const int* __restrict__ blockSums, int* __restrict__ blockBase,
                             int nb, int* __restrict__ offsets, int n) {
    int t = threadIdx.x;               // one wave, nb <= 64
    int orig = (t < nb) ? blockSums[t] : 0;
    int v = orig;
    #pragma unroll
    for (int off = 1; off < 64; off <<= 1) {
        int u = __shfl_up(v, off);
        if (t >= off) v += u;
    }
    if (t < nb) blockBase[t] = v - orig;
    if (t == nb - 1) offsets[n] = v;
}

__global__ __launch_bounds__(256) void scanC_kernel(const int* __restrict__ counts,
                                                    const int* __restrict__ blockBase,
                                                    int* __restrict__ offsets, int n) {
    __shared__ int red[256];
    int b = blockIdx.x, t = threadIdx.x;
    int base = b * 1024;
    int c[4]; int s = 0;
    #pragma unroll
    for (int j = 0; j < 4; j++) {
        int i = base + t * 4 + j;
        c[j] = (i < n) ? ((counts[i] + 7) & ~7) : 0;
        s += c[j];
    }
    red[t] = s; __syncthreads();
    for (int off = 1; off < 256; off <<= 1) {
        int u = (t >= off) ? red[t - off] : 0;
        __syncthreads();
        red[t] += u;
        __syncthreads();
    }
    int excl = red[t] - s + blockBase[b];
    #pragma unroll
    for (int j = 0; j < 4; j++) {
        int i = base + t * 4 + j;
        if (i < n) offsets[i] = excl;
        excl += c[j];
    }
}

__global__ __launch_bounds__(256) void scatter_kernel(const int* __restrict__ src,
                                                      const int* __restrict__ dst,
                                                      const int* __restrict__ offsets,
                                                      int* cursor, int* csr_src, int E, int N) {
    int id = blockIdx.x * 256 + threadIdx.x;
    if (id >= E + N) return;
    int d, s;
    if (id < E) { d = dst[id]; s = src[id]; }
    else        { d = id - E; s = d; }      // self-loop
    int pos = offsets[d] + atomicAdd(&cursor[d], 1);
    csr_src[pos] = s;
}

// ---------------- Layer 1 GEMM via MFMA (bf16) + attention dots ----------------
// D-tile = W-frag(A) x X-frag(B): lane -> node = l&15, channels t*16 + quad*4 + r
// (channels contiguous per lane -> direct ushort4 store into [node][256] layout)

__global__ __launch_bounds__(256) void gemm1_mfma_kernel(
    const unsigned short* __restrict__ Xbf, const unsigned short* __restrict__ W1T,
    const float* __restrict__ att_src, const float* __restrict__ att_dst,
    unsigned short* __restrict__ xh1_bf, float* __restrict__ a_src1, float* __restrict__ a_dst1,
    int N)
{
    __shared__ unsigned short As[64 * 72];    // 64 nodes x 64 k (pitch 72)
    __shared__ unsigned short Bs[256 * 72];   // 256 ch  x 64 k (pitch 72)
    int t  = threadIdx.x;
    int n0 = blockIdx.x * 64;

    // stage A (X rows): 512 x 16B chunks
    #pragma unroll
    for (int c = 0; c < 2; c++) {
        int idx = c * 256 + t;
        int row = idx >> 3, seg = idx & 7;
        int gr = n0 + row; if (gr >= N) gr = N - 1;
        *(uint4*)&As[row * 72 + seg * 8] = *(const uint4*)&Xbf[(size_t)gr * 64 + seg * 8];
    }
    // stage B (W1T): 2048 x 16B chunks
    #pragma unroll
    for (int c = 0; c < 8; c++) {
        int idx = c * 256 + t;
        int row = idx >> 3, seg = idx & 7;
        *(uint4*)&Bs[row * 72 + seg * 8] = *(const uint4*)&W1T[row * 64 + seg * 8];
    }
    __syncthreads();

    int w = t >> 6, l = t & 63;
    int quad = l >> 4, lm = l & 15;

    bf8 xf0 = *(const bf8*)&As[(w * 16 + lm) * 72 + quad * 8];
    bf8 xf1 = *(const bf8*)&As[(w * 16 + lm) * 72 + 32 + quad * 8];

    v4 acc[16];
    #pragma unroll
    for (int tt = 0; tt < 16; tt++) {
        bf8 wf0 = *(const bf8*)&Bs[(tt * 16 + lm) * 72 + quad * 8];
        bf8 wf1 = *(const bf8*)&Bs[(tt * 16 + lm) * 72 + 32 + quad * 8];
        v4 a = (v4)0.f;
        a = __builtin_amdgcn_mfma_f32_16x16x32_bf16(wf0, xf0, a, 0, 0, 0);
        a = __builtin_amdgcn_mfma_f32_16x16x32_bf16(wf1, xf1, a, 0, 0, 0);
        acc[tt] = a;
    }

    int node = n0 + w * 16 + lm;
    float vs[4] = {0.f, 0.f, 0.f, 0.f}, vd[4] = {0.f, 0.f, 0.f, 0.f};
    #pragma unroll
    for (int tt = 0; tt < 16; tt++) {
        int ch = tt * 16 + quad * 4;
        v4 d = acc[tt];
        v4 as_ = *(const v4*)&att_src[ch];
        v4 ad_ = *(const v4*)&att_dst[ch];
        int h = tt >> 2;
        #pragma unroll
        for (int r = 0; r < 4; r++) { vs[h] += d[r] * as_[r]; vd[h] += d[r] * ad_[r]; }
        ushort4 b; b.x = f2bf(d[0]); b.y = f2bf(d[1]); b.z = f2bf(d[2]); b.w = f2bf(d[3]);
        if (node < N) *(ushort4*)&xh1_bf[(size_t)node * 256 + ch] = b;
    }
    #pragma unroll
    for (int h = 0; h < 4; h++) {
        vs[h] += __shfl_xor(vs[h], 16); vs[h] += __shfl_xor(vs[h], 32);
        vd[h] += __shfl_xor(vd[h], 16); vd[h] += __shfl_xor(vd[h], 32);
    }
    if (l < 16 && node < N) {
        v4 o0; o0[0] = vs[0]; o0[1] = vs[1]; o0[2] = vs[2]; o0[3] = vs[3];
        v4 o1; o1[0] = vd[0]; o1[1] = vd[1]; o1[2] = vd[2]; o1[3] = vd[3];
        *(v4*)&a_src1[node * 4] = o0;
        *(v4*)&a_dst1[node * 4] = o1;
    }
}

// ---------------- Layer 1 softmax coefficients ----------------

__global__ __launch_bounds__(256) void coeff1_kernel(
    const int* __restrict__ offsets, const int* __restrict__ counts,
    int* __restrict__ csr_src,
    const float* __restrict__ a_src1, const float* __restrict__ a_dst1,
    float* __restrict__ coeff)
{
    int wid  = threadIdx.x >> 6;
    int lane = threadIdx.x & 63;
    int n = blockIdx.x * 4 + wid;
    int beg = offsets[n];
    int cnt = counts[n];
    int degp = (cnt + 7) & ~7;
    v4 adst = *(const v4*)&a_dst1[n * 4];

    v4 m = (v4)(-1e30f);
    for (int q = lane; q < cnt; q += 64) {
        int s = csr_src[beg + q];
        v4 e = *(const v4*)&a_src1[s * 4];
        #pragma unroll
        for (int c = 0; c < 4; c++) { float x = e[c] + adst[c]; e[c] = leaky02(x); m[c] = fmaxf(m[c], e[c]); }
    }
    #pragma unroll
    for (int off = 32; off; off >>= 1)
        #pragma unroll
        for (int c = 0; c < 4; c++) m[c] = fmaxf(m[c], __shfl_xor(m[c], off));

    v4 den = (v4)0.f;
    if (cnt <= 64) {
        v4 ex = (v4)0.f;
        bool act = lane < cnt;
        if (act) {
            int s = csr_src[beg + lane];
            v4 e = *(const v4*)&a_src1[s * 4];
            #pragma unroll
            for (int c = 0; c < 4; c++) ex[c] = __expf(leaky02(e[c] + adst[c]) - m[c]);
            den = ex;
        }
        #pragma unroll
        for (int off = 32; off; off >>= 1)
            #pragma unroll
            for (int c = 0; c < 4; c++) den[c] += __shfl_xor(den[c], off);
        v4 inv;
        #pragma unroll
        for (int c = 0; c < 4; c++) inv[c] = 1.f / den[c];
        if (act) {
            v4 w;
            #pragma unroll
            for (int c = 0; c < 4; c++) w[c] = ex[c] * inv[c];
            *(v4*)&coeff[(size_t)(beg + lane) * 4] = w;
        }
    } else {
        for (int q = lane; q < cnt; q += 64) {
            int s = csr_src[beg + q];
            v4 e = *(const v4*)&a_src1[s * 4], ex;
            #pragma unroll
            for (int c = 0; c < 4; c++) { ex[c] = __expf(leaky02(e[c] + adst[c]) - m[c]); den[c] += ex[c]; }
            *(v4*)&coeff[(size_t)(beg + q) * 4] = ex;
        }
        #pragma unroll
        for (int off = 32; off; off >>= 1)
            #pragma unroll
            for (int c = 0; c < 4; c++) den[c] += __shfl_xor(den[c], off);
        v4 inv;
        #pragma unroll
        for (int c = 0; c < 4; c++) inv[c] = 1.f / den[c];
        for (int q = lane; q < cnt; q += 64) {
            v4 w = *(const v4*)&coeff[(size_t)(beg + q) * 4];
            #pragma unroll
            for (int c = 0; c < 4; c++) w[c] *= inv[c];
            *(v4*)&coeff[(size_t)(beg + q) * 4] = w;
        }
    }
    int q = cnt + lane;
    if (q < degp) {
        csr_src[beg + q] = n;
        *(v4*)&coeff[(size_t)(beg + q) * 4] = (v4)0.f;
    }
}

// ---------------- Layer 1 aggregation: bf16 gather, 3-stage pipeline, bf16 H out ----------------

__global__ __launch_bounds__(256) void agg1b_kernel(
    const int* __restrict__ offsets, const int* __restrict__ csr_src,
    const float* __restrict__ coeff, const unsigned short* __restrict__ xh,
    const float* __restrict__ b1, unsigned short* __restrict__ Hbf)
{
    int wid  = threadIdx.x >> 6;
    int lane = threadIdx.x & 63;
    int n = blockIdx.x * 4 + wid;
    int beg   = offsets[n];
    int steps = (offsets[n + 1] - beg) >> 2;
    int h  = lane >> 4;
    int c0 = lane * 4;

    v4 acc = (v4)0.f;
    int s0[4], s1[4], s2[4]; float w0[4], w1[4], w2[4];
    ushort4 x0[4], x1[4];

    #pragma unroll
    for (int k = 0; k < 4; k++) {
        int idx = beg + k;
        s0[k] = csr_src[idx]; w0[k] = coeff[idx * 4 + h];
    }
    {
        int c1 = (1 < steps) ? 1 : 0;
        #pragma unroll
        for (int k = 0; k < 4; k++) {
            int idx = beg + c1 * 4 + k;
            s1[k] = csr_src[idx]; w1[k] = coeff[idx * 4 + h];
        }
    }
    #pragma unroll
    for (int k = 0; k < 4; k++) x0[k] = *(const ushort4*)&xh[(size_t)s0[k] * 256 + c0];

    for (int i = 0; i < steps; i++) {
        int i2 = (i + 2 < steps) ? i + 2 : steps - 1;
        #pragma unroll
        for (int k = 0; k < 4; k++) {
            int idx = beg + i2 * 4 + k;
            s2[k] = csr_src[idx]; w2[k] = coeff[idx * 4 + h];
        }
        if (i + 1 < steps) {
            #pragma unroll
            for (int k = 0; k < 4; k++) x1[k] = *(const ushort4*)&xh[(size_t)s1[k] * 256 + c0];
        }
        #pragma unroll
        for (int k = 0; k < 4; k++) acc += w0[k] * bf4tof(x0[k]);
        #pragma unroll
        for (int k = 0; k < 4; k++) {
            x0[k] = x1[k]; w0[k] = w1[k];
            s1[k] = s2[k]; w1[k] = w2[k];
        }
    }
    v4 bias = *(const v4*)&b1[c0];
    v4 o = acc + bias;
    ushort4 hb; hb.x = f2bf(o[0]); hb.y = f2bf(o[1]); hb.z = f2bf(o[2]); hb.w = f2bf(o[3]);
    *(ushort4*)&Hbf[(size_t)n * 256 + c0] = hb;
}

// ---------------- Layer 2 GEMM via MFMA (bf16) + attention dots ----------------

__global__ __launch_bounds__(256) void gemm2_mfma_kernel(
    const unsigned short* __restrict__ Hbf, const unsigned short* __restrict__ W2T,
    const float* __restrict__ att_src, const float* __restrict__ att_dst,
    unsigned short* __restrict__ xh2_bf, float* __restrict__ a_src2, float* __restrict__ a_dst2,
    int N)
{
    __shared__ unsigned short As[64 * 72];    // 64 nodes x 64 k
    __shared__ unsigned short Bs[128 * 72];   // 128 ch  x 64 k
    int t  = threadIdx.x;
    int n0 = blockIdx.x * 64;
    int w = t >> 6, l = t & 63;
    int quad = l >> 4, lm = l & 15;

    v4 acc[8];
    #pragma unroll
    for (int tt = 0; tt < 8; tt++) acc[tt] = (v4)0.f;

    for (int kt = 0; kt < 256; kt += 64) {
        __syncthreads();
        #pragma unroll
        for (int c = 0; c < 2; c++) {
            int idx = c * 256 + t;
            int row = idx >> 3, seg = idx & 7;
            int gr = n0 + row; if (gr >= N) gr = N - 1;
            *(uint4*)&As[row * 72 + seg * 8] = *(const uint4*)&Hbf[(size_t)gr * 256 + kt + seg * 8];
        }
        #pragma unroll
        for (int c = 0; c < 4; c++) {
            int idx = c * 256 + t;
            int row = idx >> 3, seg = idx & 7;
            *(uint4*)&Bs[row * 72 + seg * 8] = *(const uint4*)&W2T[row * 256 + kt + seg * 8];
        }
        __syncthreads();

        bf8 xf0 = *(const bf8*)&As[(w * 16 + lm) * 72 + quad * 8];
        bf8 xf1 = *(const bf8*)&As[(w * 16 + lm) * 72 + 32 + quad * 8];
        #pragma unroll
        for (int tt = 0; tt < 8; tt++) {
            bf8 wf0 = *(const bf8*)&Bs[(tt * 16 + lm) * 72 + quad * 8];
            bf8 wf1 = *(const bf8*)&Bs[(tt * 16 + lm) * 72 + 32 + quad * 8];
            acc[tt] = __builtin_amdgcn_mfma_f32_16x16x32_bf16(wf0, xf0, acc[tt], 0, 0, 0);
            acc[tt] = __builtin_amdgcn_mfma_f32_16x16x32_bf16(wf1, xf1, acc[tt], 0, 0, 0);
        }
    }

    int node = n0 + w * 16 + lm;
    float vs = 0.f, vd = 0.f;
    #pragma unroll
    for (int tt = 0; tt < 8; tt++) {
        int ch = tt * 16 + quad * 4;
        v4 d = acc[tt];
        v4 as_ = *(const v4*)&att_src[ch];
        v4 ad_ = *(const v4*)&att_dst[ch];
        #pragma unroll
        for (int r = 0; r < 4; r++) { vs += d[r] * as_[r]; vd += d[r] * ad_[r]; }
        ushort4 b; b.x = f2bf(d[0]); b.y = f2bf(d[1]); b.z = f2bf(d[2]); b.w = f2bf(d[3]);
        if (node < N) *(ushort4*)&xh2_bf[(size_t)node * 128 + ch] = b;
    }
    vs += __shfl_xor(vs, 16); vs += __shfl_xor(vs, 32);
    vd += __shfl_xor(vd, 16); vd += __shfl_xor(vd, 32);
    if (l < 16 && node < N) { a_src2[node] = vs; a_dst2[node] = vd; }
}

// ---------------- Layer 2 softmax coefficients (1 head) ----------------

__global__ __launch_bounds__(256) void coeff2_kernel(
    const int* __restrict__ offsets, const int* __restrict__ counts,
    const int* __restrict__ csr_src,
    const float* __restrict__ a_src2, const float* __restrict__ a_dst2,
    float* __restrict__ coeff)
{
    int wid  = threadIdx.x >> 6;
    int lane = threadIdx.x & 63;
    int n = blockIdx.x * 4 + wid;
    int beg = offsets[n];
    int cnt = counts[n];
    int degp = (cnt + 7) & ~7;
    float adst = a_dst2[n];

    float m = -1e30f;
    for (int q = lane; q < cnt; q += 64) {
        int s = csr_src[beg + q];
        m = fmaxf(m, leaky02(a_src2[s] + adst));
    }
    #pragma unroll
    for (int off = 32; off; off >>= 1) m = fmaxf(m, __shfl_xor(m, off));

    float den = 0.f;
    if (cnt <= 64) {
        float ex = 0.f;
        bool act = lane < cnt;
        if (act) {
            int s = csr_src[beg + lane];
            ex = __expf(leaky02(a_src2[s] + adst) - m);
            den = ex;
        }
        #pragma unroll
        for (int off = 32; off; off >>= 1) den += __shfl_xor(den, off);
        float inv = 1.f / den;
        if (act) coeff[beg + lane] = ex * inv;
    } else {
        for (int q = lane; q < cnt; q += 64) {
            int s = csr_src[beg + q];
            float ex = __expf(leaky02(a_src2[s] + adst) - m);
            coeff[beg + q] = ex;
            den += ex;
        }
        #pragma unroll
        for (int off = 32; off; off >>= 1) den += __shfl_xor(den, off);
        float inv = 1.f / den;
        for (int q = lane; q < cnt; q += 64) coeff[beg + q] *= inv;
    }
    int q = cnt + lane;
    if (q < degp) coeff[beg + q] = 0.f;
}

// ---------------- Layer 2 aggregation: bf16 gather, 2 edges/load, pipelined ----------------

__global__ __launch_bounds__(256) void agg2b_kernel(
    const int* __restrict__ offsets, const int* __restrict__ csr_src,
    const float* __restrict__ coeff, const unsigned short* __restrict__ xh2,
    const float* __restrict__ b2, float* __restrict__ out)
{
    int wid  = threadIdx.x >> 6;
    int lane = threadIdx.x & 63;
    int n = blockIdx.x * 4 + wid;
    int beg   = offsets[n];
    int steps = (offsets[n + 1] - beg) >> 3;
    int hh = lane >> 5;
    int c0 = (lane & 31) * 4;

    v4 acc = (v4)0.f;
    int s0[4], s1[4], s2[4]; float w0[4], w1[4], w2[4];
    ushort4 x0[4], x1[4];

    #pragma unroll
    for (int k = 0; k < 4; k++) {
        int idx = beg + 2 * k + hh;
        s0[k] = csr_src[idx]; w0[k] = coeff[idx];
    }
    {
        int c1 = (1 < steps) ? 1 : 0;
        #pragma unroll
        for (int k = 0; k < 4; k++) {
            int idx = beg + c1 * 8 + 2 * k + hh;
            s1[k] = csr_src[idx]; w1[k] = coeff[idx];
        }
    }
    #pragma unroll
    for (int k = 0; k < 4; k++) x0[k] = *(const ushort4*)&xh2[(size_t)s0[k] * 128 + c0];

    for (int i = 0; i < steps; i++) {
        int i2 = (i + 2 < steps) ? i + 2 : steps - 1;
        #pragma unroll
        for (int k = 0; k < 4; k++) {
            int idx = beg + i2 * 8 + 2 * k + hh;
            s2[k] = csr_src[idx]; w2[k] = coeff[idx];
        }
        if (i + 1 < steps) {
            #pragma unroll
            for (int k = 0; k < 4; k++) x1[k] = *(const ushort4*)&xh2[(size_t)s1[k] * 128 + c0];
        }
        #pragma unroll
        for (int k = 0; k < 4; k++) acc += w0[k] * bf4tof(x0[k]);
        #pragma unroll
        for (int k = 0; k < 4; k++) {
            x0[k] = x1[k]; w0[k] = w1[k];
            s1[k] = s2[k]; w1[k] = w2[k];
        }
    }
    #pragma unroll
    for (int c = 0; c < 4; c++) acc[c] += __shfl_xor(acc[c], 32);
    if (lane < 32) {
        v4 bias = *(const v4*)&b2[c0];
        *(v4*)&out[(size_t)n * 128 + c0] = acc + bias;
    }
}

// ---------------- launcher ----------------

static inline size_t rnd256(size_t x) { return (x + 255) & ~(size_t)255; }

extern "C" void kernel_launch(void* const* d_in, const int* in_sizes, int n_in,
                              void* d_out, int out_size, void* d_ws, size_t ws_size,
                              hipStream_t stream) {
    const float* X   = (const float*)d_in[0];
    const int*   ei  = (const int*)d_in[1];
    const float* W1  = (const float*)d_in[2];
    const float* as1 = (const float*)d_in[3];
    const float* ad1 = (const float*)d_in[4];
    const float* b1  = (const float*)d_in[5];
    const float* W2  = (const float*)d_in[6];
    const float* as2 = (const float*)d_in[7];
    const float* ad2 = (const float*)d_in[8];
    const float* b2  = (const float*)d_in[9];
    float* out = (float*)d_out;

    const int N = in_sizes[0] / 64;   // 50000
    const int E = in_sizes[1] / 2;    // 800000
    const int* srcArr = ei;
    const int* dstArr = ei + E;
    const size_t CSRMAX = (size_t)E + 8 * (size_t)N;
    const int NB = (N + 1023) / 1024;
    const int NBLK = (N + 63) / 64;

    char* w = (char*)d_ws;
    unsigned short* Xbf    = (unsigned short*)w;  w += rnd256((size_t)N * 64 * 2);
    unsigned short* W1T    = (unsigned short*)w;  w += rnd256((size_t)256 * 64 * 2);
    unsigned short* W2T    = (unsigned short*)w;  w += rnd256((size_t)128 * 256 * 2);
    unsigned short* xh1_bf = (unsigned short*)w;  w += rnd256((size_t)N * 256 * 2);
    unsigned short* Hbf    = (unsigned short*)w;  w += rnd256((size_t)N * 256 * 2);
    float* a_src1  = (float*)w;  w += rnd256((size_t)N * 4 * 4);
    float* a_dst1  = (float*)w;  w += rnd256((size_t)N * 4 * 4);
    float* a_src2v = (float*)w;  w += rnd256((size_t)N * 4);
    float* a_dst2v = (float*)w;  w += rnd256((size_t)N * 4);
    int*   counts  = (int*)w;    w += rnd256((size_t)N * 4);
    int*   offsets = (int*)w;    w += rnd256((size_t)(N + 1) * 4);
    int*   cursor  = (int*)w;    w += rnd256((size_t)N * 4);
    int*   blockSums = (int*)w;  w += rnd256((size_t)NB * 4);
    int*   blockBase = (int*)w;  w += rnd256((size_t)NB * 4);
    int*   csr_src = (int*)w;    w += rnd256(CSRMAX * 4);
    float* coeffA  = (float*)w;  w += rnd256(CSRMAX * 4 * 4);
    unsigned short* xh2_bf = xh1_bf;  // dead after agg1b
    float* coeffB  = coeffA;          // dead after agg1b

    // CSR build
    init_kernel<<<(N + 255) / 256, 256, 0, stream>>>(counts, cursor, N);
    hist_kernel<<<(E + 255) / 256, 256, 0, stream>>>(dstArr, counts, E);
    scanA_kernel<<<NB, 256, 0, stream>>>(counts, blockSums, N);
    scanB_kernel<<<1, 64, 0, stream>>>(blockSums, blockBase, NB, offsets, N);
    scanC_kernel<<<NB, 256, 0, stream>>>(counts, blockBase, offsets, N);
    scatter_kernel<<<(E + N + 255) / 256, 256, 0, stream>>>(srcArr, dstArr, offsets, cursor,
                                                            csr_src, E, N);
    // precision prep
    convX_kernel<<<(N * 64 / 8 + 255) / 256, 256, 0, stream>>>(X, Xbf, N * 64);
    convWT_kernel<<<(64 * 256 + 255) / 256, 256, 0, stream>>>(W1, W1T, 64, 256);
    convWT_kernel<<<(256 * 128 + 255) / 256, 256, 0, stream>>>(W2, W2T, 256, 128);
    // layer 1
    gemm1_mfma_kernel<<<NBLK, 256, 0, stream>>>(Xbf, W1T, as1, ad1, xh1_bf, a_src1, a_dst1, N);
    coeff1_kernel<<<N / 4, 256, 0, stream>>>(offsets, counts, csr_src, a_src1, a_dst1, coeffA);
    agg1b_kernel<<<N / 4, 256, 0, stream>>>(offsets, csr_src, coeffA, xh1_bf, b1, Hbf);
    // layer 2
    gemm2_mfma_kernel<<<NBLK, 256, 0, stream>>>(Hbf, W2T, as2, ad2, xh2_bf, a_src2v, a_dst2v, N);
    coeff2_kernel<<<N / 4, 256, 0, stream>>>(offsets, counts, csr_src, a_src2v, a_dst2v, coeffB);
    agg2b_kernel<<<N / 4, 256, 0, stream>>>(offsets, csr_src, coeffB, xh2_bf, b2, out);
}

// Round 5
// 321.081 us; speedup vs baseline: 2.5909x; 1.1569x over previous
//
#include <hip/hip_runtime.h>
#include <hip/hip_bf16.h>

typedef float v4 __attribute__((ext_vector_type(4)));
typedef short bf8 __attribute__((ext_vector_type(8)));

__device__ __forceinline__ unsigned short f2bf(float f) {   // RNE fp32->bf16
    unsigned u = __float_as_uint(f);
    unsigned r = (u + 0x7fffu + ((u >> 16) & 1u)) >> 16;
    return (unsigned short)r;
}
__device__ __forceinline__ v4 bf4tof(ushort4 u) {
    v4 r;
    r[0] = __uint_as_float(((unsigned)u.x) << 16);
    r[1] = __uint_as_float(((unsigned)u.y) << 16);
    r[2] = __uint_as_float(((unsigned)u.z) << 16);
    r[3] = __uint_as_float(((unsigned)u.w) << 16);
    return r;
}
// uint4 = 8 bf16 channels (memory order) -> two v4 (ch0..3, ch4..7)
__device__ __forceinline__ void unp8(uint4 u, v4& lo, v4& hi) {
    lo[0] = __uint_as_float(u.x << 16); lo[1] = __uint_as_float(u.x & 0xffff0000u);
    lo[2] = __uint_as_float(u.y << 16); lo[3] = __uint_as_float(u.y & 0xffff0000u);
    hi[0] = __uint_as_float(u.z << 16); hi[1] = __uint_as_float(u.z & 0xffff0000u);
    hi[2] = __uint_as_float(u.w << 16); hi[3] = __uint_as_float(u.w & 0xffff0000u);
}
__device__ __forceinline__ float leaky02(float x) { return x >= 0.f ? x : 0.2f * x; }

// ---------------- fused precision prep: X->bf16, W1->W1T bf16, W2->W2T bf16 ----------------

__global__ __launch_bounds__(256) void conv_all_kernel(
    const float* __restrict__ X, const float* __restrict__ W1, const float* __restrict__ W2,
    unsigned short* __restrict__ Xbf, unsigned short* __restrict__ W1T,
    unsigned short* __restrict__ W2T, int XB, int NX)
{
    int b = blockIdx.x, t = threadIdx.x;
    if (b < XB) {
        int i = (b * 256 + t) * 8;
        if (i < NX) {
            float4 a = *(const float4*)&X[i];
            float4 c = *(const float4*)&X[i + 4];
            ushort4 r0; r0.x = f2bf(a.x); r0.y = f2bf(a.y); r0.z = f2bf(a.z); r0.w = f2bf(a.w);
            ushort4 r1; r1.x = f2bf(c.x); r1.y = f2bf(c.y); r1.z = f2bf(c.z); r1.w = f2bf(c.w);
            *(ushort4*)&Xbf[i] = r0;
            *(ushort4*)&Xbf[i + 4] = r1;
        }
    } else if (b < XB + 64) {
        int id = (b - XB) * 256 + t;      // [256 out][64 k]
        int j = id >> 6, k = id & 63;
        W1T[id] = f2bf(W1[k * 256 + j]);
    } else {
        int id = (b - XB - 64) * 256 + t; // [128 out][256 k]
        int j = id >> 8, k = id & 255;
        W2T[id] = f2bf(W2[k * 128 + j]);
    }
}

// ---------------- CSR build (degree padded to multiple of 8) ----------------

__global__ __launch_bounds__(256) void init_kernel(int* counts, int* cursor, int N) {
    int i = blockIdx.x * 256 + threadIdx.x;
    if (i < N) { counts[i] = 1; /* self-loop */ cursor[i] = 0; }
}

__global__ __launch_bounds__(256) void hist_kernel(const int* __restrict__ dst, int* counts, int E) {
    int e = blockIdx.x * 256 + threadIdx.x;
    if (e < E) atomicAdd(&counts[dst[e]], 1);
}

__global__ __launch_bounds__(256) void scanA_kernel(const int* __restrict__ counts,
                                                    int* __restrict__ blockSums, int n) {
    __shared__ int red[256];
    int b = blockIdx.x, t = threadIdx.x;
    int base = b * 1024;
    int s = 0;
    #pragma unroll
    for (int j = 0; j < 4; j++) {
        int i = base + j * 256 + t;
        if (i < n) s += (counts[i] + 7) & ~7;
    }
    red[t] = s; __syncthreads();
    for (int off = 128; off; off >>= 1) { if (t < off) red[t] += red[t + off]; __syncthreads(); }
    if (t == 0) blockSums[b] = red[0];
}

__global__ void scanB_kernel(const int* __restrict__ blockSums, int* __restrict__ blockBase,
                             int nb, int* __restrict__ offsets, int n) {
    int t = threadIdx.x;               // one wave, nb <= 64
    int orig = (t < nb) ? blockSums[t] : 0;
    int v = orig;
    #pragma unroll
    for (int off = 1; off < 64; off <<= 1) {
        int u = __shfl_up(v, off);
        if (t >= off) v += u;
    }
    if (t < nb) blockBase[t] = v - orig;
    if (t == nb - 1) offsets[n] = v;
}

__global__ __launch_bounds__(256) void scanC_kernel(const int* __restrict__ counts,
                                                    const int* __restrict__ blockBase,
                                                    int* __restrict__ offsets, int n) {
    __shared__ int red[256];
    int b = blockIdx.x, t = threadIdx.x;
    int base = b * 1024;
    int c[4]; int s = 0;
    #pragma unroll
    for (int j = 0; j < 4; j++) {
        int i = base + t * 4 + j;
        c[j] = (i < n) ? ((counts[i] + 7) & ~7) : 0;
        s += c[j];
    }
    red[t] = s; __syncthreads();
    for (int off = 1; off < 256; off <<= 1) {
        int u = (t >= off) ? red[t - off] : 0;
        __syncthreads();
        red[t] += u;
        __syncthreads();
    }
    int excl = red[t] - s + blockBase[b];
    #pragma unroll
    for (int j = 0; j < 4; j++) {
        int i = base + t * 4 + j;
        if (i < n) offsets[i] = excl;
        excl += c[j];
    }
}

// scatter edges + self-loops, plus pad-slot fill (src=self) in extra blocks
__global__ __launch_bounds__(256) void scatter_kernel(const int* __restrict__ src,
                                                      const int* __restrict__ dst,
                                                      const int* __restrict__ offsets,
                                                      const int* __restrict__ counts,
                                                      int* cursor, int* csr_src,
                                                      int E, int N, int EB) {
    if ((int)blockIdx.x < EB) {
        int id = blockIdx.x * 256 + threadIdx.x;
        if (id >= E + N) return;
        int d, s;
        if (id < E) { d = dst[id]; s = src[id]; }
        else        { d = id - E; s = d; }      // self-loop
        int pos = offsets[d] + atomicAdd(&cursor[d], 1);
        csr_src[pos] = s;
    } else {
        int i = (blockIdx.x - EB) * 256 + threadIdx.x;
        if (i >= N) return;
        int beg = offsets[i];
        int cnt = counts[i];
        int degp = (cnt + 7) & ~7;
        for (int q = cnt; q < degp; q++) csr_src[beg + q] = i;  // pad -> self (w masked to 0)
    }
}

// ---------------- Layer 1 GEMM via MFMA (bf16) + attention dots ----------------

__global__ __launch_bounds__(256) void gemm1_mfma_kernel(
    const unsigned short* __restrict__ Xbf, const unsigned short* __restrict__ W1T,
    const float* __restrict__ att_src, const float* __restrict__ att_dst,
    unsigned short* __restrict__ xh1_bf, float* __restrict__ a_src1, float* __restrict__ a_dst1,
    int N)
{
    __shared__ unsigned short As[64 * 72];    // 64 nodes x 64 k (pitch 72)
    __shared__ unsigned short Bs[256 * 72];   // 256 ch  x 64 k (pitch 72)
    int t  = threadIdx.x;
    int n0 = blockIdx.x * 64;

    #pragma unroll
    for (int c = 0; c < 2; c++) {
        int idx = c * 256 + t;
        int row = idx >> 3, seg = idx & 7;
        int gr = n0 + row; if (gr >= N) gr = N - 1;
        *(uint4*)&As[row * 72 + seg * 8] = *(const uint4*)&Xbf[(size_t)gr * 64 + seg * 8];
    }
    #pragma unroll
    for (int c = 0; c < 8; c++) {
        int idx = c * 256 + t;
        int row = idx >> 3, seg = idx & 7;
        *(uint4*)&Bs[row * 72 + seg * 8] = *(const uint4*)&W1T[row * 64 + seg * 8];
    }
    __syncthreads();

    int w = t >> 6, l = t & 63;
    int quad = l >> 4, lm = l & 15;

    bf8 xf0 = *(const bf8*)&As[(w * 16 + lm) * 72 + quad * 8];
    bf8 xf1 = *(const bf8*)&As[(w * 16 + lm) * 72 + 32 + quad * 8];

    v4 acc[16];
    #pragma unroll
    for (int tt = 0; tt < 16; tt++) {
        bf8 wf0 = *(const bf8*)&Bs[(tt * 16 + lm) * 72 + quad * 8];
        bf8 wf1 = *(const bf8*)&Bs[(tt * 16 + lm) * 72 + 32 + quad * 8];
        v4 a = (v4)0.f;
        a = __builtin_amdgcn_mfma_f32_16x16x32_bf16(wf0, xf0, a, 0, 0, 0);
        a = __builtin_amdgcn_mfma_f32_16x16x32_bf16(wf1, xf1, a, 0, 0, 0);
        acc[tt] = a;
    }

    int node = n0 + w * 16 + lm;
    float vs[4] = {0.f, 0.f, 0.f, 0.f}, vd[4] = {0.f, 0.f, 0.f, 0.f};
    #pragma unroll
    for (int tt = 0; tt < 16; tt++) {
        int ch = tt * 16 + quad * 4;
        v4 d = acc[tt];
        v4 as_ = *(const v4*)&att_src[ch];
        v4 ad_ = *(const v4*)&att_dst[ch];
        int h = tt >> 2;
        #pragma unroll
        for (int r = 0; r < 4; r++) { vs[h] += d[r] * as_[r]; vd[h] += d[r] * ad_[r]; }
        ushort4 b; b.x = f2bf(d[0]); b.y = f2bf(d[1]); b.z = f2bf(d[2]); b.w = f2bf(d[3]);
        if (node < N) *(ushort4*)&xh1_bf[(size_t)node * 256 + ch] = b;
    }
    #pragma unroll
    for (int h = 0; h < 4; h++) {
        vs[h] += __shfl_xor(vs[h], 16); vs[h] += __shfl_xor(vs[h], 32);
        vd[h] += __shfl_xor(vd[h], 16); vd[h] += __shfl_xor(vd[h], 32);
    }
    if (l < 16 && node < N) {
        v4 o0; o0[0] = vs[0]; o0[1] = vs[1]; o0[2] = vs[2]; o0[3] = vs[3];
        v4 o1; o1[0] = vd[0]; o1[1] = vd[1]; o1[2] = vd[2]; o1[3] = vd[3];
        *(v4*)&a_src1[node * 4] = o0;
        *(v4*)&a_dst1[node * 4] = o1;
    }
}

// ---------------- Layer 1 fused softmax+aggregation (single pass, no segment max) ----------------
// one wave per node; hh=lane>>5 edge parity; lane covers 8 channels (16B bf16 loads).
// w = exp(clamp(leaky(a_src+a_dst),80)); unnormalized accumulate; divide by den at end.
// Safe: logits here are O(1); clamp only engages where ref would overflow too (never).

__global__ __launch_bounds__(256) void aggf1_kernel(
    const int* __restrict__ offsets, const int* __restrict__ counts,
    const int* __restrict__ csr_src,
    const float* __restrict__ a_src1, const float* __restrict__ a_dst1,
    const unsigned short* __restrict__ xh, const float* __restrict__ b1,
    unsigned short* __restrict__ Hbf)
{
    int wid  = threadIdx.x >> 6;
    int lane = threadIdx.x & 63;
    int n = blockIdx.x * 4 + wid;
    int beg   = offsets[n];
    int cnt   = counts[n];
    int steps = (offsets[n + 1] - beg) >> 3;   // chunks of 8 edges (4 slots x 2)
    int hh = lane >> 5;
    int cl = lane & 31;
    int c0 = cl * 8;
    int h  = cl >> 3;
    float adst = a_dst1[n * 4 + h];

    v4 accL = (v4)0.f, accH = (v4)0.f;
    float den = 0.f;
    int s0[4], s1[4], s2[4];
    float a0[4], a1[4];
    uint4 x0[4], x1[4];

    #pragma unroll
    for (int k = 0; k < 4; k++) s0[k] = csr_src[beg + 2 * k + hh];
    {
        int c1 = (1 < steps) ? 1 : 0;
        #pragma unroll
        for (int k = 0; k < 4; k++) s1[k] = csr_src[beg + c1 * 8 + 2 * k + hh];
    }
    #pragma unroll
    for (int k = 0; k < 4; k++) {
        x0[k] = *(const uint4*)&xh[(size_t)s0[k] * 256 + c0];
        a0[k] = a_src1[s0[k] * 4 + h];
    }

    for (int i = 0; i < steps; i++) {
        int i2 = (i + 2 < steps) ? i + 2 : steps - 1;
        #pragma unroll
        for (int k = 0; k < 4; k++) s2[k] = csr_src[beg + i2 * 8 + 2 * k + hh];
        if (i + 1 < steps) {
            #pragma unroll
            for (int k = 0; k < 4; k++) {
                x1[k] = *(const uint4*)&xh[(size_t)s1[k] * 256 + c0];
                a1[k] = a_src1[s1[k] * 4 + h];
            }
        }
        int qb = i * 8 + hh;
        #pragma unroll
        for (int k = 0; k < 4; k++) {
            float e = fminf(leaky02(a0[k] + adst), 80.f);
            float w = (qb + 2 * k < cnt) ? __expf(e) : 0.f;
            den += w;
            v4 lo, hi; unp8(x0[k], lo, hi);
            accL += w * lo; accH += w * hi;
        }
        #pragma unroll
        for (int k = 0; k < 4; k++) {
            x0[k] = x1[k]; a0[k] = a1[k];
            s1[k] = s2[k];
        }
    }

    den += __shfl_xor(den, 32);
    #pragma unroll
    for (int c = 0; c < 4; c++) { accL[c] += __shfl_xor(accL[c], 32); accH[c] += __shfl_xor(accH[c], 32); }
    if (lane < 32) {
        float inv = 1.f / den;
        v4 bl = *(const v4*)&b1[c0];
        v4 bh = *(const v4*)&b1[c0 + 4];
        v4 oL = accL * inv + bl;
        v4 oH = accH * inv + bh;
        uint4 pk;
        pk.x = (unsigned)f2bf(oL[0]) | ((unsigned)f2bf(oL[1]) << 16);
        pk.y = (unsigned)f2bf(oL[2]) | ((unsigned)f2bf(oL[3]) << 16);
        pk.z = (unsigned)f2bf(oH[0]) | ((unsigned)f2bf(oH[1]) << 16);
        pk.w = (unsigned)f2bf(oH[2]) | ((unsigned)f2bf(oH[3]) << 16);
        *(uint4*)&Hbf[(size_t)n * 256 + c0] = pk;
    }
}

// ---------------- Layer 2 GEMM via MFMA (bf16) + attention dots ----------------

__global__ __launch_bounds__(256) void gemm2_mfma_kernel(
    const unsigned short* __restrict__ Hbf, const unsigned short* __restrict__ W2T,
    const float* __restrict__ att_src, const float* __restrict__ att_dst,
    unsigned short* __restrict__ xh2_bf, float* __restrict__ a_src2, float* __restrict__ a_dst2,
    int N)
{
    __shared__ unsigned short As[64 * 72];
    __shared__ unsigned short Bs[128 * 72];
    int t  = threadIdx.x;
    int n0 = blockIdx.x * 64;
    int w = t >> 6, l = t & 63;
    int quad = l >> 4, lm = l & 15;

    v4 acc[8];
    #pragma unroll
    for (int tt = 0; tt < 8; tt++) acc[tt] = (v4)0.f;

    for (int kt = 0; kt < 256; kt += 64) {
        __syncthreads();
        #pragma unroll
        for (int c = 0; c < 2; c++) {
            int idx = c * 256 + t;
            int row = idx >> 3, seg = idx & 7;
            int gr = n0 + row; if (gr >= N) gr = N - 1;
            *(uint4*)&As[row * 72 + seg * 8] = *(const uint4*)&Hbf[(size_t)gr * 256 + kt + seg * 8];
        }
        #pragma unroll
        for (int c = 0; c < 4; c++) {
            int idx = c * 256 + t;
            int row = idx >> 3, seg = idx & 7;
            *(uint4*)&Bs[row * 72 + seg * 8] = *(const uint4*)&W2T[row * 256 + kt + seg * 8];
        }
        __syncthreads();

        bf8 xf0 = *(const bf8*)&As[(w * 16 + lm) * 72 + quad * 8];
        bf8 xf1 = *(const bf8*)&As[(w * 16 + lm) * 72 + 32 + quad * 8];
        #pragma unroll
        for (int tt = 0; tt < 8; tt++) {
            bf8 wf0 = *(const bf8*)&Bs[(tt * 16 + lm) * 72 + quad * 8];
            bf8 wf1 = *(const bf8*)&Bs[(tt * 16 + lm) * 72 + 32 + quad * 8];
            acc[tt] = __builtin_amdgcn_mfma_f32_16x16x32_bf16(wf0, xf0, acc[tt], 0, 0, 0);
            acc[tt] = __builtin_amdgcn_mfma_f32_16x16x32_bf16(wf1, xf1, acc[tt], 0, 0, 0);
        }
    }

    int node = n0 + w * 16 + lm;
    float vs = 0.f, vd = 0.f;
    #pragma unroll
    for (int tt = 0; tt < 8; tt++) {
        int ch = tt * 16 + quad * 4;
        v4 d = acc[tt];
        v4 as_ = *(const v4*)&att_src[ch];
        v4 ad_ = *(const v4*)&att_dst[ch];
        #pragma unroll
        for (int r = 0; r < 4; r++) { vs += d[r] * as_[r]; vd += d[r] * ad_[r]; }
        ushort4 b; b.x = f2bf(d[0]); b.y = f2bf(d[1]); b.z = f2bf(d[2]); b.w = f2bf(d[3]);
        if (node < N) *(ushort4*)&xh2_bf[(size_t)node * 128 + ch] = b;
    }
    vs += __shfl_xor(vs, 16); vs += __shfl_xor(vs, 32);
    vd += __shfl_xor(vd, 16); vd += __shfl_xor(vd, 32);
    if (l < 16 && node < N) { a_src2[node] = vs; a_dst2[node] = vd; }
}

// ---------------- Layer 2 fused softmax+aggregation (single pass) ----------------
// hh=lane>>5 edge parity; lane covers 4 channels (8B bf16 loads); chunk 8 edges.

__global__ __launch_bounds__(256) void aggf2_kernel(
    const int* __restrict__ offsets, const int* __restrict__ counts,
    const int* __restrict__ csr_src,
    const float* __restrict__ a_src2, const float* __restrict__ a_dst2,
    const unsigned short* __restrict__ xh2, const float* __restrict__ b2,
    float* __restrict__ out)
{
    int wid  = threadIdx.x >> 6;
    int lane = threadIdx.x & 63;
    int n = blockIdx.x * 4 + wid;
    int beg   = offsets[n];
    int cnt   = counts[n];
    int steps = (offsets[n + 1] - beg) >> 3;
    int hh = lane >> 5;
    int c0 = (lane & 31) * 4;
    float adst = a_dst2[n];

    v4 acc = (v4)0.f;
    float den = 0.f;
    int s0[4], s1[4], s2[4];
    float a0[4], a1[4];
    ushort4 x0[4], x1[4];

    #pragma unroll
    for (int k = 0; k < 4; k++) s0[k] = csr_src[beg + 2 * k + hh];
    {
        int c1 = (1 < steps) ? 1 : 0;
        #pragma unroll
        for (int k = 0; k < 4; k++) s1[k] = csr_src[beg + c1 * 8 + 2 * k + hh];
    }
    #pragma unroll
    for (int k = 0; k < 4; k++) {
        x0[k] = *(const ushort4*)&xh2[(size_t)s0[k] * 128 + c0];
        a0[k] = a_src2[s0[k]];
    }

    for (int i = 0; i < steps; i++) {
        int i2 = (i + 2 < steps) ? i + 2 : steps - 1;
        #pragma unroll
        for (int k = 0; k < 4; k++) s2[k] = csr_src[beg + i2 * 8 + 2 * k + hh];
        if (i + 1 < steps) {
            #pragma unroll
            for (int k = 0; k < 4; k++) {
                x1[k] = *(const ushort4*)&xh2[(size_t)s1[k] * 128 + c0];
                a1[k] = a_src2[s1[k]];
            }
        }
        int qb = i * 8 + hh;
        #pragma unroll
        for (int k = 0; k < 4; k++) {
            float e = fminf(leaky02(a0[k] + adst), 80.f);
            float w = (qb + 2 * k < cnt) ? __expf(e) : 0.f;
            den += w;
            acc += w * bf4tof(x0[k]);
        }
        #pragma unroll
        for (int k = 0; k < 4; k++) {
            x0[k] = x1[k]; a0[k] = a1[k];
            s1[k] = s2[k];
        }
    }

    den += __shfl_xor(den, 32);
    #pragma unroll
    for (int c = 0; c < 4; c++) acc[c] += __shfl_xor(acc[c], 32);
    if (lane < 32) {
        v4 bias = *(const v4*)&b2[c0];
        *(v4*)&out[(size_t)n * 128 + c0] = acc * (1.f / den) + bias;
    }
}

// ---------------- launcher ----------------

static inline size_t rnd256(size_t x) { return (x + 255) & ~(size_t)255; }

extern "C" void kernel_launch(void* const* d_in, const int* in_sizes, int n_in,
                              void* d_out, int out_size, void* d_ws, size_t ws_size,
                              hipStream_t stream) {
    const float* X   = (const float*)d_in[0];
    const int*   ei  = (const int*)d_in[1];
    const float* W1  = (const float*)d_in[2];
    const float* as1 = (const float*)d_in[3];
    const float* ad1 = (const float*)d_in[4];
    const float* b1  = (const float*)d_in[5];
    const float* W2  = (const float*)d_in[6];
    const float* as2 = (const float*)d_in[7];
    const float* ad2 = (const float*)d_in[8];
    const float* b2  = (const float*)d_in[9];
    float* out = (float*)d_out;

    const int N = in_sizes[0] / 64;   // 50000
    const int E = in_sizes[1] / 2;    // 800000
    const int* srcArr = ei;
    const int* dstArr = ei + E;
    const size_t CSRMAX = (size_t)E + 8 * (size_t)N;
    const int NB = (N + 1023) / 1024;
    const int NBLK = (N + 63) / 64;
    const int EB = (E + N + 255) / 256;
    const int PB = (N + 255) / 256;
    const int XB = (N * 64 / 8 + 255) / 256;

    char* w = (char*)d_ws;
    unsigned short* Xbf    = (unsigned short*)w;  w += rnd256((size_t)N * 64 * 2);
    unsigned short* W1T    = (unsigned short*)w;  w += rnd256((size_t)256 * 64 * 2);
    unsigned short* W2T    = (unsigned short*)w;  w += rnd256((size_t)128 * 256 * 2);
    unsigned short* xh1_bf = (unsigned short*)w;  w += rnd256((size_t)N * 256 * 2);
    unsigned short* Hbf    = (unsigned short*)w;  w += rnd256((size_t)N * 256 * 2);
    float* a_src1  = (float*)w;  w += rnd256((size_t)N * 4 * 4);
    float* a_dst1  = (float*)w;  w += rnd256((size_t)N * 4 * 4);
    float* a_src2v = (float*)w;  w += rnd256((size_t)N * 4);
    float* a_dst2v = (float*)w;  w += rnd256((size_t)N * 4);
    int*   counts  = (int*)w;    w += rnd256((size_t)N * 4);
    int*   offsets = (int*)w;    w += rnd256((size_t)(N + 1) * 4);
    int*   cursor  = (int*)w;    w += rnd256((size_t)N * 4);
    int*   blockSums = (int*)w;  w += rnd256((size_t)NB * 4);
    int*   blockBase = (int*)w;  w += rnd256((size_t)NB * 4);
    int*   csr_src = (int*)w;    w += rnd256(CSRMAX * 4);
    unsigned short* xh2_bf = xh1_bf;  // dead after aggf1

    // CSR build
    init_kernel<<<(N + 255) / 256, 256, 0, stream>>>(counts, cursor, N);
    hist_kernel<<<(E + 255) / 256, 256, 0, stream>>>(dstArr, counts, E);
    scanA_kernel<<<NB, 256, 0, stream>>>(counts, blockSums, N);
    scanB_kernel<<<1, 64, 0, stream>>>(blockSums, blockBase, NB, offsets, N);
    scanC_kernel<<<NB, 256, 0, stream>>>(counts, blockBase, offsets, N);
    scatter_kernel<<<EB + PB, 256, 0, stream>>>(srcArr, dstArr, offsets, counts, cursor,
                                                csr_src, E, N, EB);
    // precision prep (fused)
    conv_all_kernel<<<XB + 64 + 128, 256, 0, stream>>>(X, W1, W2, Xbf, W1T, W2T, XB, N * 64);
    // layer 1
    gemm1_mfma_kernel<<<NBLK, 256, 0, stream>>>(Xbf, W1T, as1, ad1, xh1_bf, a_src1, a_dst1, N);
    aggf1_kernel<<<N / 4, 256, 0, stream>>>(offsets, counts, csr_src, a_src1, a_dst1,
                                            xh1_bf, b1, Hbf);
    // layer 2
    gemm2_mfma_kernel<<<NBLK, 256, 0, stream>>>(Hbf, W2T, as2, ad2, xh2_bf, a_src2v, a_dst2v, N);
    aggf2_kernel<<<N / 4, 256, 0, stream>>>(offsets, counts, csr_src, a_src2v, a_dst2v,
                                            xh2_bf, b2, out);
}

// Round 6
// 319.447 us; speedup vs baseline: 2.6041x; 1.0051x over previous
//
#include <hip/hip_runtime.h>
#include <hip/hip_bf16.h>
#include <hip/hip_fp16.h>

typedef float v4 __attribute__((ext_vector_type(4)));
typedef _Float16 hv8 __attribute__((ext_vector_type(8)));
typedef _Float16 h2 __attribute__((ext_vector_type(2)));

__device__ __forceinline__ unsigned short f2h(float f) {
    _Float16 h = (_Float16)f;
    return __builtin_bit_cast(unsigned short, h);
}
__device__ __forceinline__ float h2f_lo(h2 v) { return (float)v[0]; }
__device__ __forceinline__ float leaky02(float x) { return x >= 0.f ? x : 0.2f * x; }

// ---------------- fused prep: X->f16, W1T/W2T f16, counts/cursor init ----------------

__global__ __launch_bounds__(256) void conv_init_kernel(
    const float* __restrict__ X, const float* __restrict__ W1, const float* __restrict__ W2,
    unsigned short* __restrict__ Xh, unsigned short* __restrict__ W1T,
    unsigned short* __restrict__ W2T, int* __restrict__ counts, int* __restrict__ cursor,
    int XB, int NX, int N)
{
    int b = blockIdx.x, t = threadIdx.x;
    if (b < XB) {
        int i = (b * 256 + t) * 8;
        if (i < NX) {
            float4 a = *(const float4*)&X[i];
            float4 c = *(const float4*)&X[i + 4];
            ushort4 r0; r0.x = f2h(a.x); r0.y = f2h(a.y); r0.z = f2h(a.z); r0.w = f2h(a.w);
            ushort4 r1; r1.x = f2h(c.x); r1.y = f2h(c.y); r1.z = f2h(c.z); r1.w = f2h(c.w);
            *(ushort4*)&Xh[i] = r0;
            *(ushort4*)&Xh[i + 4] = r1;
        }
    } else if (b < XB + 64) {
        int id = (b - XB) * 256 + t;      // [256 out][64 k]
        int j = id >> 6, k = id & 63;
        W1T[id] = f2h(W1[k * 256 + j]);
    } else if (b < XB + 64 + 128) {
        int id = (b - XB - 64) * 256 + t; // [128 out][256 k]
        int j = id >> 8, k = id & 255;
        W2T[id] = f2h(W2[k * 128 + j]);
    } else {
        int i = (b - XB - 64 - 128) * 256 + t;
        if (i < N) { counts[i] = 1; cursor[i] = 0; }
    }
}

// ---------------- CSR build (degree padded to multiple of 8) ----------------

__global__ __launch_bounds__(256) void hist_kernel(const int* __restrict__ dst, int* counts, int E) {
    int e = blockIdx.x * 256 + threadIdx.x;
    if (e < E) atomicAdd(&counts[dst[e]], 1);
}

__global__ __launch_bounds__(256) void scanA_kernel(const int* __restrict__ counts,
                                                    int* __restrict__ blockSums, int n) {
    __shared__ int red[256];
    int b = blockIdx.x, t = threadIdx.x;
    int base = b * 1024;
    int s = 0;
    #pragma unroll
    for (int j = 0; j < 4; j++) {
        int i = base + j * 256 + t;
        if (i < n) s += (counts[i] + 7) & ~7;
    }
    red[t] = s; __syncthreads();
    for (int off = 128; off; off >>= 1) { if (t < off) red[t] += red[t + off]; __syncthreads(); }
    if (t == 0) blockSums[b] = red[0];
}

// scanC with inlined cross-block scan (each block redundantly scans blockSums; nb <= 64)
__global__ __launch_bounds__(256) void scanC_kernel(const int* __restrict__ counts,
                                                    const int* __restrict__ blockSums,
                                                    int* __restrict__ offsets, int n, int nb) {
    __shared__ int red[256];
    __shared__ int base_s;
    int b = blockIdx.x, t = threadIdx.x;
    if (t < 64) {
        int v = (t < nb) ? blockSums[t] : 0;
        #pragma unroll
        for (int off = 1; off < 64; off <<= 1) {
            int u = __shfl_up(v, off);
            if (t >= off) v += u;
        }
        int basev = (b == 0) ? 0 : __shfl(v, b - 1);
        int tot = __shfl(v, nb - 1);
        if (t == 0) {
            base_s = basev;
            if (b == 0) offsets[n] = tot;
        }
    }
    int base = b * 1024;
    int c[4]; int s = 0;
    #pragma unroll
    for (int j = 0; j < 4; j++) {
        int i = base + t * 4 + j;
        c[j] = (i < n) ? ((counts[i] + 7) & ~7) : 0;
        s += c[j];
    }
    red[t] = s; __syncthreads();
    for (int off = 1; off < 256; off <<= 1) {
        int u = (t >= off) ? red[t - off] : 0;
        __syncthreads();
        red[t] += u;
        __syncthreads();
    }
    int excl = red[t] - s + base_s;
    #pragma unroll
    for (int j = 0; j < 4; j++) {
        int i = base + t * 4 + j;
        if (i < n) offsets[i] = excl;
        excl += c[j];
    }
}

// scatter edges + self-loops, plus pad-slot fill (src=self) in extra blocks
__global__ __launch_bounds__(256) void scatter_kernel(const int* __restrict__ src,
                                                      const int* __restrict__ dst,
                                                      const int* __restrict__ offsets,
                                                      const int* __restrict__ counts,
                                                      int* cursor, int* csr_src,
                                                      int E, int N, int EB) {
    if ((int)blockIdx.x < EB) {
        int id = blockIdx.x * 256 + threadIdx.x;
        if (id >= E + N) return;
        int d, s;
        if (id < E) { d = dst[id]; s = src[id]; }
        else        { d = id - E; s = d; }      // self-loop
        int pos = offsets[d] + atomicAdd(&cursor[d], 1);
        csr_src[pos] = s;
    } else {
        int i = (blockIdx.x - EB) * 256 + threadIdx.x;
        if (i >= N) return;
        int beg = offsets[i];
        int cnt = counts[i];
        int degp = (cnt + 7) & ~7;
        for (int q = cnt; q < degp; q++) csr_src[beg + q] = i;  // pad -> self (w masked to 0)
    }
}

// ---------------- Layer 1 GEMM via MFMA (f16) + attention dots ----------------

__global__ __launch_bounds__(256) void gemm1_mfma_kernel(
    const unsigned short* __restrict__ Xh, const unsigned short* __restrict__ W1T,
    const float* __restrict__ att_src, const float* __restrict__ att_dst,
    unsigned short* __restrict__ xh1, float* __restrict__ a_src1, float* __restrict__ a_dst1,
    int N)
{
    __shared__ unsigned short As[64 * 72];    // 64 nodes x 64 k (pitch 72)
    __shared__ unsigned short Bs[256 * 72];   // 256 ch  x 64 k (pitch 72)
    int t  = threadIdx.x;
    int n0 = blockIdx.x * 64;

    #pragma unroll
    for (int c = 0; c < 2; c++) {
        int idx = c * 256 + t;
        int row = idx >> 3, seg = idx & 7;
        int gr = n0 + row; if (gr >= N) gr = N - 1;
        *(uint4*)&As[row * 72 + seg * 8] = *(const uint4*)&Xh[(size_t)gr * 64 + seg * 8];
    }
    #pragma unroll
    for (int c = 0; c < 8; c++) {
        int idx = c * 256 + t;
        int row = idx >> 3, seg = idx & 7;
        *(uint4*)&Bs[row * 72 + seg * 8] = *(const uint4*)&W1T[row * 64 + seg * 8];
    }
    __syncthreads();

    int w = t >> 6, l = t & 63;
    int quad = l >> 4, lm = l & 15;

    hv8 xf0 = *(const hv8*)&As[(w * 16 + lm) * 72 + quad * 8];
    hv8 xf1 = *(const hv8*)&As[(w * 16 + lm) * 72 + 32 + quad * 8];

    v4 acc[16];
    #pragma unroll
    for (int tt = 0; tt < 16; tt++) {
        hv8 wf0 = *(const hv8*)&Bs[(tt * 16 + lm) * 72 + quad * 8];
        hv8 wf1 = *(const hv8*)&Bs[(tt * 16 + lm) * 72 + 32 + quad * 8];
        v4 a = (v4)0.f;
        a = __builtin_amdgcn_mfma_f32_16x16x32_f16(wf0, xf0, a, 0, 0, 0);
        a = __builtin_amdgcn_mfma_f32_16x16x32_f16(wf1, xf1, a, 0, 0, 0);
        acc[tt] = a;
    }

    int node = n0 + w * 16 + lm;
    float vs[4] = {0.f, 0.f, 0.f, 0.f}, vd[4] = {0.f, 0.f, 0.f, 0.f};
    #pragma unroll
    for (int tt = 0; tt < 16; tt++) {
        int ch = tt * 16 + quad * 4;
        v4 d = acc[tt];
        v4 as_ = *(const v4*)&att_src[ch];
        v4 ad_ = *(const v4*)&att_dst[ch];
        int h = tt >> 2;
        #pragma unroll
        for (int r = 0; r < 4; r++) { vs[h] += d[r] * as_[r]; vd[h] += d[r] * ad_[r]; }
        ushort4 b; b.x = f2h(d[0]); b.y = f2h(d[1]); b.z = f2h(d[2]); b.w = f2h(d[3]);
        if (node < N) *(ushort4*)&xh1[(size_t)node * 256 + ch] = b;
    }
    #pragma unroll
    for (int h = 0; h < 4; h++) {
        vs[h] += __shfl_xor(vs[h], 16); vs[h] += __shfl_xor(vs[h], 32);
        vd[h] += __shfl_xor(vd[h], 16); vd[h] += __shfl_xor(vd[h], 32);
    }
    if (l < 16 && node < N) {
        v4 o0; o0[0] = vs[0]; o0[1] = vs[1]; o0[2] = vs[2]; o0[3] = vs[3];
        v4 o1; o1[0] = vd[0]; o1[1] = vd[1]; o1[2] = vd[2]; o1[3] = vd[3];
        *(v4*)&a_src1[node * 4] = o0;
        *(v4*)&a_dst1[node * 4] = o1;
    }
}

// ---------------- Layer 1 fused softmax+aggregation (f16 packed math) ----------------
// one wave per node; hh=lane>>5 edge parity; lane covers 8 channels (16B f16 loads).
// w = exp(min(leaky(a_src+a_dst),11)) rounded to f16 (fits: e^11=59874<65504); packed
// f16 multiply-acc within each 8-edge chunk, flushed to fp32 per chunk.

__global__ __launch_bounds__(256) void aggf1_kernel(
    const int* __restrict__ offsets, const int* __restrict__ counts,
    const int* __restrict__ csr_src,
    const float* __restrict__ a_src1, const float* __restrict__ a_dst1,
    const unsigned short* __restrict__ xh, const float* __restrict__ b1,
    unsigned short* __restrict__ Hh)
{
    int wid  = threadIdx.x >> 6;
    int lane = threadIdx.x & 63;
    int n = blockIdx.x * 4 + wid;
    int beg   = offsets[n];
    int cnt   = counts[n];
    int steps = (offsets[n + 1] - beg) >> 3;   // chunks of 8 edges (4 slots x 2 parity)
    int hh = lane >> 5;
    int cl = lane & 31;
    int c0 = cl * 8;
    int h  = cl >> 3;
    float adst = a_dst1[n * 4 + h];

    v4 accL = (v4)0.f, accH = (v4)0.f;
    float den = 0.f;
    int s0[4], s1[4], s2[4];
    float a0[4], a1[4];
    uint4 x0[4], x1[4];

    #pragma unroll
    for (int k = 0; k < 4; k++) s0[k] = csr_src[beg + 2 * k + hh];
    {
        int c1 = (1 < steps) ? 1 : 0;
        #pragma unroll
        for (int k = 0; k < 4; k++) s1[k] = csr_src[beg + c1 * 8 + 2 * k + hh];
    }
    #pragma unroll
    for (int k = 0; k < 4; k++) {
        x0[k] = *(const uint4*)&xh[(size_t)s0[k] * 256 + c0];
        a0[k] = a_src1[s0[k] * 4 + h];
    }

    for (int i = 0; i < steps; i++) {
        int i2 = (i + 2 < steps) ? i + 2 : steps - 1;
        #pragma unroll
        for (int k = 0; k < 4; k++) s2[k] = csr_src[beg + i2 * 8 + 2 * k + hh];
        if (i + 1 < steps) {
            #pragma unroll
            for (int k = 0; k < 4; k++) {
                x1[k] = *(const uint4*)&xh[(size_t)s1[k] * 256 + c0];
                a1[k] = a_src1[s1[k] * 4 + h];
            }
        }
        int qb = i * 8 + hh;
        h2 ah[4] = {(h2)(_Float16)0.f, (h2)(_Float16)0.f, (h2)(_Float16)0.f, (h2)(_Float16)0.f};
        #pragma unroll
        for (int k = 0; k < 4; k++) {
            float e = fminf(leaky02(a0[k] + adst), 11.f);
            float w = (qb + 2 * k < cnt) ? __expf(e) : 0.f;
            _Float16 wh = (_Float16)w;
            den += (float)wh;
            h2 wv; wv[0] = wh; wv[1] = wh;
            const h2* xp = (const h2*)&x0[k];
            #pragma unroll
            for (int j = 0; j < 4; j++) ah[j] += wv * xp[j];
        }
        accL[0] += (float)ah[0][0]; accL[1] += (float)ah[0][1];
        accL[2] += (float)ah[1][0]; accL[3] += (float)ah[1][1];
        accH[0] += (float)ah[2][0]; accH[1] += (float)ah[2][1];
        accH[2] += (float)ah[3][0]; accH[3] += (float)ah[3][1];
        #pragma unroll
        for (int k = 0; k < 4; k++) {
            x0[k] = x1[k]; a0[k] = a1[k];
            s1[k] = s2[k];
        }
    }

    den += __shfl_xor(den, 32);
    #pragma unroll
    for (int c = 0; c < 4; c++) { accL[c] += __shfl_xor(accL[c], 32); accH[c] += __shfl_xor(accH[c], 32); }
    if (lane < 32) {
        float inv = 1.f / den;
        v4 bl = *(const v4*)&b1[c0];
        v4 bh = *(const v4*)&b1[c0 + 4];
        v4 oL = accL * inv + bl;
        v4 oH = accH * inv + bh;
        uint4 pk;
        pk.x = (unsigned)f2h(oL[0]) | ((unsigned)f2h(oL[1]) << 16);
        pk.y = (unsigned)f2h(oL[2]) | ((unsigned)f2h(oL[3]) << 16);
        pk.z = (unsigned)f2h(oH[0]) | ((unsigned)f2h(oH[1]) << 16);
        pk.w = (unsigned)f2h(oH[2]) | ((unsigned)f2h(oH[3]) << 16);
        *(uint4*)&Hh[(size_t)n * 256 + c0] = pk;
    }
}

// ---------------- Layer 2 GEMM via MFMA (f16) + attention dots ----------------

__global__ __launch_bounds__(256) void gemm2_mfma_kernel(
    const unsigned short* __restrict__ Hh, const unsigned short* __restrict__ W2T,
    const float* __restrict__ att_src, const float* __restrict__ att_dst,
    unsigned short* __restrict__ xh2, float* __restrict__ a_src2, float* __restrict__ a_dst2,
    int N)
{
    __shared__ unsigned short As[64 * 72];
    __shared__ unsigned short Bs[128 * 72];
    int t  = threadIdx.x;
    int n0 = blockIdx.x * 64;
    int w = t >> 6, l = t & 63;
    int quad = l >> 4, lm = l & 15;

    v4 acc[8];
    #pragma unroll
    for (int tt = 0; tt < 8; tt++) acc[tt] = (v4)0.f;

    for (int kt = 0; kt < 256; kt += 64) {
        __syncthreads();
        #pragma unroll
        for (int c = 0; c < 2; c++) {
            int idx = c * 256 + t;
            int row = idx >> 3, seg = idx & 7;
            int gr = n0 + row; if (gr >= N) gr = N - 1;
            *(uint4*)&As[row * 72 + seg * 8] = *(const uint4*)&Hh[(size_t)gr * 256 + kt + seg * 8];
        }
        #pragma unroll
        for (int c = 0; c < 4; c++) {
            int idx = c * 256 + t;
            int row = idx >> 3, seg = idx & 7;
            *(uint4*)&Bs[row * 72 + seg * 8] = *(const uint4*)&W2T[row * 256 + kt + seg * 8];
        }
        __syncthreads();

        hv8 xf0 = *(const hv8*)&As[(w * 16 + lm) * 72 + quad * 8];
        hv8 xf1 = *(const hv8*)&As[(w * 16 + lm) * 72 + 32 + quad * 8];
        #pragma unroll
        for (int tt = 0; tt < 8; tt++) {
            hv8 wf0 = *(const hv8*)&Bs[(tt * 16 + lm) * 72 + quad * 8];
            hv8 wf1 = *(const hv8*)&Bs[(tt * 16 + lm) * 72 + 32 + quad * 8];
            acc[tt] = __builtin_amdgcn_mfma_f32_16x16x32_f16(wf0, xf0, acc[tt], 0, 0, 0);
            acc[tt] = __builtin_amdgcn_mfma_f32_16x16x32_f16(wf1, xf1, acc[tt], 0, 0, 0);
        }
    }

    int node = n0 + w * 16 + lm;
    float vs = 0.f, vd = 0.f;
    #pragma unroll
    for (int tt = 0; tt < 8; tt++) {
        int ch = tt * 16 + quad * 4;
        v4 d = acc[tt];
        v4 as_ = *(const v4*)&att_src[ch];
        v4 ad_ = *(const v4*)&att_dst[ch];
        #pragma unroll
        for (int r = 0; r < 4; r++) { vs += d[r] * as_[r]; vd += d[r] * ad_[r]; }
        ushort4 b; b.x = f2h(d[0]); b.y = f2h(d[1]); b.z = f2h(d[2]); b.w = f2h(d[3]);
        if (node < N) *(ushort4*)&xh2[(size_t)node * 128 + ch] = b;
    }
    vs += __shfl_xor(vs, 16); vs += __shfl_xor(vs, 32);
    vd += __shfl_xor(vd, 16); vd += __shfl_xor(vd, 32);
    if (l < 16 && node < N) { a_src2[node] = vs; a_dst2[node] = vd; }
}

// ---------------- Layer 2 fused softmax+aggregation (f16, 16B loads, 4 parities) ----------------
// hh=lane>>4 parity (4 edges in parallel); lane covers 8 channels (16B); chunk 8 edges.

__global__ __launch_bounds__(256) void aggf2_kernel(
    const int* __restrict__ offsets, const int* __restrict__ counts,
    const int* __restrict__ csr_src,
    const float* __restrict__ a_src2, const float* __restrict__ a_dst2,
    const unsigned short* __restrict__ xh2, const float* __restrict__ b2,
    float* __restrict__ out)
{
    int wid  = threadIdx.x >> 6;
    int lane = threadIdx.x & 63;
    int n = blockIdx.x * 4 + wid;
    int beg   = offsets[n];
    int cnt   = counts[n];
    int steps = (offsets[n + 1] - beg) >> 3;
    int hh = lane >> 4;
    int c0 = (lane & 15) * 8;
    float adst = a_dst2[n];

    v4 accL = (v4)0.f, accH = (v4)0.f;
    float den = 0.f;
    int s0[2], s1[2], s2[2];
    float a0[2], a1[2];
    uint4 x0[2], x1[2];

    #pragma unroll
    for (int k = 0; k < 2; k++) s0[k] = csr_src[beg + 4 * k + hh];
    {
        int c1 = (1 < steps) ? 1 : 0;
        #pragma unroll
        for (int k = 0; k < 2; k++) s1[k] = csr_src[beg + c1 * 8 + 4 * k + hh];
    }
    #pragma unroll
    for (int k = 0; k < 2; k++) {
        x0[k] = *(const uint4*)&xh2[(size_t)s0[k] * 128 + c0];
        a0[k] = a_src2[s0[k]];
    }

    for (int i = 0; i < steps; i++) {
        int i2 = (i + 2 < steps) ? i + 2 : steps - 1;
        #pragma unroll
        for (int k = 0; k < 2; k++) s2[k] = csr_src[beg + i2 * 8 + 4 * k + hh];
        if (i + 1 < steps) {
            #pragma unroll
            for (int k = 0; k < 2; k++) {
                x1[k] = *(const uint4*)&xh2[(size_t)s1[k] * 128 + c0];
                a1[k] = a_src2[s1[k]];
            }
        }
        int qb = i * 8 + hh;
        h2 ah[4] = {(h2)(_Float16)0.f, (h2)(_Float16)0.f, (h2)(_Float16)0.f, (h2)(_Float16)0.f};
        #pragma unroll
        for (int k = 0; k < 2; k++) {
            float e = fminf(leaky02(a0[k] + adst), 11.f);
            float w = (qb + 4 * k < cnt) ? __expf(e) : 0.f;
            _Float16 wh = (_Float16)w;
            den += (float)wh;
            h2 wv; wv[0] = wh; wv[1] = wh;
            const h2* xp = (const h2*)&x0[k];
            #pragma unroll
            for (int j = 0; j < 4; j++) ah[j] += wv * xp[j];
        }
        accL[0] += (float)ah[0][0]; accL[1] += (float)ah[0][1];
        accL[2] += (float)ah[1][0]; accL[3] += (float)ah[1][1];
        accH[0] += (float)ah[2][0]; accH[1] += (float)ah[2][1];
        accH[2] += (float)ah[3][0]; accH[3] += (float)ah[3][1];
        #pragma unroll
        for (int k = 0; k < 2; k++) {
            x0[k] = x1[k]; a0[k] = a1[k];
            s1[k] = s2[k];
        }
    }

    den += __shfl_xor(den, 16); den += __shfl_xor(den, 32);
    #pragma unroll
    for (int c = 0; c < 4; c++) {
        accL[c] += __shfl_xor(accL[c], 16); accL[c] += __shfl_xor(accL[c], 32);
        accH[c] += __shfl_xor(accH[c], 16); accH[c] += __shfl_xor(accH[c], 32);
    }
    if (lane < 16) {
        float inv = 1.f / den;
        v4 bl = *(const v4*)&b2[c0];
        v4 bh = *(const v4*)&b2[c0 + 4];
        *(v4*)&out[(size_t)n * 128 + c0]     = accL * inv + bl;
        *(v4*)&out[(size_t)n * 128 + c0 + 4] = accH * inv + bh;
    }
}

// ---------------- launcher ----------------

static inline size_t rnd256(size_t x) { return (x + 255) & ~(size_t)255; }

extern "C" void kernel_launch(void* const* d_in, const int* in_sizes, int n_in,
                              void* d_out, int out_size, void* d_ws, size_t ws_size,
                              hipStream_t stream) {
    const float* X   = (const float*)d_in[0];
    const int*   ei  = (const int*)d_in[1];
    const float* W1  = (const float*)d_in[2];
    const float* as1 = (const float*)d_in[3];
    const float* ad1 = (const float*)d_in[4];
    const float* b1  = (const float*)d_in[5];
    const float* W2  = (const float*)d_in[6];
    const float* as2 = (const float*)d_in[7];
    const float* ad2 = (const float*)d_in[8];
    const float* b2  = (const float*)d_in[9];
    float* out = (float*)d_out;

    const int N = in_sizes[0] / 64;   // 50000
    const int E = in_sizes[1] / 2;    // 800000
    const int* srcArr = ei;
    const int* dstArr = ei + E;
    const size_t CSRMAX = (size_t)E + 8 * (size_t)N;
    const int NB = (N + 1023) / 1024;
    const int NBLK = (N + 63) / 64;
    const int EB = (E + N + 255) / 256;
    const int PB = (N + 255) / 256;
    const int XB = (N * 64 / 8 + 255) / 256;
    const int IB = (N + 255) / 256;

    char* w = (char*)d_ws;
    unsigned short* Xh     = (unsigned short*)w;  w += rnd256((size_t)N * 64 * 2);
    unsigned short* W1T    = (unsigned short*)w;  w += rnd256((size_t)256 * 64 * 2);
    unsigned short* W2T    = (unsigned short*)w;  w += rnd256((size_t)128 * 256 * 2);
    unsigned short* xh1    = (unsigned short*)w;  w += rnd256((size_t)N * 256 * 2);
    unsigned short* Hh     = (unsigned short*)w;  w += rnd256((size_t)N * 256 * 2);
    float* a_src1  = (float*)w;  w += rnd256((size_t)N * 4 * 4);
    float* a_dst1  = (float*)w;  w += rnd256((size_t)N * 4 * 4);
    float* a_src2v = (float*)w;  w += rnd256((size_t)N * 4);
    float* a_dst2v = (float*)w;  w += rnd256((size_t)N * 4);
    int*   counts  = (int*)w;    w += rnd256((size_t)N * 4);
    int*   offsets = (int*)w;    w += rnd256((size_t)(N + 1) * 4);
    int*   cursor  = (int*)w;    w += rnd256((size_t)N * 4);
    int*   blockSums = (int*)w;  w += rnd256((size_t)NB * 4);
    int*   csr_src = (int*)w;    w += rnd256(CSRMAX * 4);
    unsigned short* xh2 = xh1;   // dead after aggf1

    // prep (conv + CSR init fused)
    conv_init_kernel<<<XB + 64 + 128 + IB, 256, 0, stream>>>(X, W1, W2, Xh, W1T, W2T,
                                                             counts, cursor, XB, N * 64, N);
    // CSR build
    hist_kernel<<<(E + 255) / 256, 256, 0, stream>>>(dstArr, counts, E);
    scanA_kernel<<<NB, 256, 0, stream>>>(counts, blockSums, N);
    scanC_kernel<<<NB, 256, 0, stream>>>(counts, blockSums, offsets, N, NB);
    scatter_kernel<<<EB + PB, 256, 0, stream>>>(srcArr, dstArr, offsets, counts, cursor,
                                                csr_src, E, N, EB);
    // layer 1
    gemm1_mfma_kernel<<<NBLK, 256, 0, stream>>>(Xh, W1T, as1, ad1, xh1, a_src1, a_dst1, N);
    aggf1_kernel<<<N / 4, 256, 0, stream>>>(offsets, counts, csr_src, a_src1, a_dst1,
                                            xh1, b1, Hh);
    // layer 2
    gemm2_mfma_kernel<<<NBLK, 256, 0, stream>>>(Hh, W2T, as2, ad2, xh2, a_src2v, a_dst2v, N);
    aggf2_kernel<<<N / 4, 256, 0, stream>>>(offsets, counts, csr_src, a_src2v, a_dst2v,
                                            xh2, b2, out);
}

// Round 7
// 317.174 us; speedup vs baseline: 2.6228x; 1.0072x over previous
//
#include <hip/hip_runtime.h>
#include <hip/hip_bf16.h>
#include <hip/hip_fp16.h>

typedef float v4 __attribute__((ext_vector_type(4)));
typedef _Float16 hv8 __attribute__((ext_vector_type(8)));
typedef _Float16 h2 __attribute__((ext_vector_type(2)));

__device__ __forceinline__ unsigned short f2h(float f) {
    _Float16 h = (_Float16)f;
    return __builtin_bit_cast(unsigned short, h);
}
// uint4 = 8 f16 (memory order) -> two v4 fp32
__device__ __forceinline__ void unph8(uint4 u, v4& lo, v4& hi) {
    h2 a = __builtin_bit_cast(h2, u.x);
    h2 b = __builtin_bit_cast(h2, u.y);
    h2 c = __builtin_bit_cast(h2, u.z);
    h2 d = __builtin_bit_cast(h2, u.w);
    lo[0] = (float)a[0]; lo[1] = (float)a[1]; lo[2] = (float)b[0]; lo[3] = (float)b[1];
    hi[0] = (float)c[0]; hi[1] = (float)c[1]; hi[2] = (float)d[0]; hi[3] = (float)d[1];
}
__device__ __forceinline__ float leaky02(float x) { return x >= 0.f ? x : 0.2f * x; }

// ---- prep: X->f16, W1T/W2T f16, v = W1·att (fp32), counts/cursor init ----

__global__ __launch_bounds__(256) void conv_init_kernel(
    const float* __restrict__ X, const float* __restrict__ W1, const float* __restrict__ W2,
    const float* __restrict__ as1, const float* __restrict__ ad1,
    unsigned short* __restrict__ Xh, unsigned short* __restrict__ W1T,
    unsigned short* __restrict__ W2T, float* __restrict__ vsrc, float* __restrict__ vdst,
    int* __restrict__ counts, int* __restrict__ cursor,
    int XB, int NX, int N, int IB)
{
    int b = blockIdx.x, t = threadIdx.x;
    if (b < XB) {
        int i = (b * 256 + t) * 8;
        if (i < NX) {
            float4 a = *(const float4*)&X[i];
            float4 c = *(const float4*)&X[i + 4];
            ushort4 r0; r0.x = f2h(a.x); r0.y = f2h(a.y); r0.z = f2h(a.z); r0.w = f2h(a.w);
            ushort4 r1; r1.x = f2h(c.x); r1.y = f2h(c.y); r1.z = f2h(c.z); r1.w = f2h(c.w);
            *(ushort4*)&Xh[i] = r0;
            *(ushort4*)&Xh[i + 4] = r1;
        }
    } else if (b < XB + 64) {
        int id = (b - XB) * 256 + t;      // [256 out][64 k]
        int j = id >> 6, k = id & 63;
        W1T[id] = f2h(W1[k * 256 + j]);
    } else if (b < XB + 64 + 128) {
        int id = (b - XB - 64) * 256 + t; // [128 out][256 k]
        int j = id >> 8, k = id & 255;
        W2T[id] = f2h(W2[k * 128 + j]);
    } else if (b < XB + 64 + 128 + IB) {
        int i = (b - XB - 64 - 128) * 256 + t;
        if (i < N) { counts[i] = 1; cursor[i] = 0; }
    } else {
        // two blocks: v_src then v_dst ; t = h*64 + k
        int vb = b - (XB + 64 + 128 + IB);
        const float* att = vb ? ad1 : as1;
        float* vout = vb ? vdst : vsrc;
        int h = t >> 6, k = t & 63;
        float s = 0.f;
        const float* wrow = &W1[k * 256 + h * 64];
        const float* arow = &att[h * 64];
        #pragma unroll 8
        for (int c = 0; c < 64; c++) s += wrow[c] * arow[c];
        vout[t] = s;
    }
}

// ---------------- CSR build (degree padded to multiple of 8) ----------------

__global__ __launch_bounds__(256) void hist_kernel(const int* __restrict__ dst, int* counts, int E) {
    int e = blockIdx.x * 256 + threadIdx.x;
    if (e < E) atomicAdd(&counts[dst[e]], 1);
}

__global__ __launch_bounds__(256) void scanA_kernel(const int* __restrict__ counts,
                                                    int* __restrict__ blockSums, int n) {
    __shared__ int red[256];
    int b = blockIdx.x, t = threadIdx.x;
    int base = b * 1024;
    int s = 0;
    #pragma unroll
    for (int j = 0; j < 4; j++) {
        int i = base + j * 256 + t;
        if (i < n) s += (counts[i] + 7) & ~7;
    }
    red[t] = s; __syncthreads();
    for (int off = 128; off; off >>= 1) { if (t < off) red[t] += red[t + off]; __syncthreads(); }
    if (t == 0) blockSums[b] = red[0];
}

__global__ __launch_bounds__(256) void scanC_kernel(const int* __restrict__ counts,
                                                    const int* __restrict__ blockSums,
                                                    int* __restrict__ offsets, int n, int nb) {
    __shared__ int red[256];
    __shared__ int base_s;
    int b = blockIdx.x, t = threadIdx.x;
    if (t < 64) {
        int v = (t < nb) ? blockSums[t] : 0;
        #pragma unroll
        for (int off = 1; off < 64; off <<= 1) {
            int u = __shfl_up(v, off);
            if (t >= off) v += u;
        }
        int basev = (b == 0) ? 0 : __shfl(v, b - 1);
        int tot = __shfl(v, nb - 1);
        if (t == 0) {
            base_s = basev;
            if (b == 0) offsets[n] = tot;
        }
    }
    int base = b * 1024;
    int c[4]; int s = 0;
    #pragma unroll
    for (int j = 0; j < 4; j++) {
        int i = base + t * 4 + j;
        c[j] = (i < n) ? ((counts[i] + 7) & ~7) : 0;
        s += c[j];
    }
    red[t] = s; __syncthreads();
    for (int off = 1; off < 256; off <<= 1) {
        int u = (t >= off) ? red[t - off] : 0;
        __syncthreads();
        red[t] += u;
        __syncthreads();
    }
    int excl = red[t] - s + base_s;
    #pragma unroll
    for (int j = 0; j < 4; j++) {
        int i = base + t * 4 + j;
        if (i < n) offsets[i] = excl;
        excl += c[j];
    }
}

__global__ __launch_bounds__(256) void scatter_kernel(const int* __restrict__ src,
                                                      const int* __restrict__ dst,
                                                      const int* __restrict__ offsets,
                                                      const int* __restrict__ counts,
                                                      int* cursor, int* csr_src,
                                                      int E, int N, int EB) {
    if ((int)blockIdx.x < EB) {
        int id = blockIdx.x * 256 + threadIdx.x;
        if (id >= E + N) return;
        int d, s;
        if (id < E) { d = dst[id]; s = src[id]; }
        else        { d = id - E; s = d; }      // self-loop
        int pos = offsets[d] + atomicAdd(&cursor[d], 1);
        csr_src[pos] = s;
    } else {
        int i = (blockIdx.x - EB) * 256 + threadIdx.x;
        if (i >= N) return;
        int beg = offsets[i];
        int cnt = counts[i];
        int degp = (cnt + 7) & ~7;
        for (int q = cnt; q < degp; q++) csr_src[beg + q] = i;  // pad -> self (w masked 0)
    }
}

// ---------------- attention dots: a_src1/a_dst1 = Xh · v ----------------
// wave per 8 nodes; 8 lanes per node, 8 ch each (16B load)

__global__ __launch_bounds__(256) void attdot_kernel(
    const unsigned short* __restrict__ Xh, const float* __restrict__ vsrc,
    const float* __restrict__ vdst, float* __restrict__ a_src1, float* __restrict__ a_dst1,
    int N)
{
    __shared__ float vs[256], vd[256];
    int t = threadIdx.x;
    vs[t] = vsrc[t]; vd[t] = vdst[t];
    __syncthreads();
    int w = t >> 6, lane = t & 63;
    int nd = lane >> 3, sub = lane & 7, kc = sub * 8;
    int node = blockIdx.x * 32 + w * 8 + nd;
    if (node >= N) node = N - 1;
    uint4 x = *(const uint4*)&Xh[(size_t)node * 64 + kc];
    v4 lo, hi; unph8(x, lo, hi);
    float ps[4], pd[4];
    #pragma unroll
    for (int h = 0; h < 4; h++) {
        float s = 0.f, d = 0.f;
        #pragma unroll
        for (int j = 0; j < 4; j++) {
            s += lo[j] * vs[h * 64 + kc + j];     d += lo[j] * vd[h * 64 + kc + j];
            s += hi[j] * vs[h * 64 + kc + 4 + j]; d += hi[j] * vd[h * 64 + kc + 4 + j];
        }
        ps[h] = s; pd[h] = d;
    }
    #pragma unroll
    for (int off = 1; off < 8; off <<= 1)
        #pragma unroll
        for (int h = 0; h < 4; h++) {
            ps[h] += __shfl_xor(ps[h], off);
            pd[h] += __shfl_xor(pd[h], off);
        }
    if (sub == 0) {
        v4 o0; o0[0] = ps[0]; o0[1] = ps[1]; o0[2] = ps[2]; o0[3] = ps[3];
        v4 o1; o1[0] = pd[0]; o1[1] = pd[1]; o1[2] = pd[2]; o1[3] = pd[3];
        *(v4*)&a_src1[node * 4] = o0;
        *(v4*)&a_dst1[node * 4] = o1;
    }
}

// ---------------- Layer 1 fused softmax + X-aggregation (gathers 128B/edge) ----------------
// one wave per node; 8 parities x 8 lanes; lane = 8 X-channels (16B f16 load);
// per edge: 4 head-weights from a_src1; fp32 acc [4 heads][8 ch]; normalized f16 out.

__global__ __launch_bounds__(256) void aggX_kernel(
    const int* __restrict__ offsets, const int* __restrict__ counts,
    const int* __restrict__ csr_src,
    const float* __restrict__ a_src1, const float* __restrict__ a_dst1,
    const unsigned short* __restrict__ Xh, unsigned short* __restrict__ Xagg)
{
    int wid  = threadIdx.x >> 6;
    int lane = threadIdx.x & 63;
    int n = blockIdx.x * 4 + wid;
    int beg   = offsets[n];
    int cnt   = counts[n];
    int steps = (offsets[n + 1] - beg) >> 3;
    int p = lane >> 3, sub = lane & 7, kc = sub * 8;
    v4 adst = *(const v4*)&a_dst1[n * 4];

    v4 accL[4], accH[4];
    #pragma unroll
    for (int h = 0; h < 4; h++) { accL[h] = (v4)0.f; accH[h] = (v4)0.f; }
    v4 den = (v4)0.f;

    int s0, s1, s2;
    uint4 x0, x1;
    v4 a0, a1;

    s0 = csr_src[beg + p];
    s1 = csr_src[beg + ((1 < steps) ? 8 : 0) + p];
    x0 = *(const uint4*)&Xh[(size_t)s0 * 64 + kc];
    a0 = *(const v4*)&a_src1[s0 * 4];

    for (int i = 0; i < steps; i++) {
        int i2 = (i + 2 < steps) ? i + 2 : steps - 1;
        s2 = csr_src[beg + i2 * 8 + p];
        if (i + 1 < steps) {
            x1 = *(const uint4*)&Xh[(size_t)s1 * 64 + kc];
            a1 = *(const v4*)&a_src1[s1 * 4];
        }
        bool valid = (i * 8 + p) < cnt;
        v4 lo, hi; unph8(x0, lo, hi);
        #pragma unroll
        for (int h = 0; h < 4; h++) {
            float e = fminf(leaky02(a0[h] + adst[h]), 80.f);
            float w = valid ? __expf(e) : 0.f;
            den[h] += w;
            accL[h] += w * lo;
            accH[h] += w * hi;
        }
        x0 = x1; a0 = a1; s1 = s2;
    }

    // reduce across the 8 parities (lane bits 3,4,5)
    #pragma unroll
    for (int off = 8; off < 64; off <<= 1) {
        #pragma unroll
        for (int h = 0; h < 4; h++) {
            den[h] += __shfl_xor(den[h], off);
            #pragma unroll
            for (int c = 0; c < 4; c++) {
                accL[h][c] += __shfl_xor(accL[h][c], off);
                accH[h][c] += __shfl_xor(accH[h][c], off);
            }
        }
    }
    if (p == 0) {
        #pragma unroll
        for (int h = 0; h < 4; h++) {
            float inv = 1.f / den[h];
            v4 oL = accL[h] * inv, oH = accH[h] * inv;
            uint4 pk;
            pk.x = (unsigned)f2h(oL[0]) | ((unsigned)f2h(oL[1]) << 16);
            pk.y = (unsigned)f2h(oL[2]) | ((unsigned)f2h(oL[3]) << 16);
            pk.z = (unsigned)f2h(oH[0]) | ((unsigned)f2h(oH[1]) << 16);
            pk.w = (unsigned)f2h(oH[2]) | ((unsigned)f2h(oH[3]) << 16);
            *(uint4*)&Xagg[(size_t)n * 256 + h * 64 + kc] = pk;
        }
    }
}

// ---------------- H = Xagg (per-head) · W1 + b1, f16 out ----------------
// block: 32 nodes x 256 ch; wave w: nodes (w&1)*16.., tiles (w>>1)*8..

__global__ __launch_bounds__(256) void gemmH_kernel(
    const unsigned short* __restrict__ Xagg, const unsigned short* __restrict__ W1T,
    const float* __restrict__ b1, unsigned short* __restrict__ Hh, int N)
{
    __shared__ unsigned short As[32 * 264];   // 32 nodes x 256 (4 heads x 64), pitch 264
    __shared__ unsigned short Bs[256 * 72];   // 256 out-ch x 64 k, pitch 72
    int t  = threadIdx.x;
    int n0 = blockIdx.x * 32;

    #pragma unroll
    for (int c = 0; c < 4; c++) {
        int idx = c * 256 + t;
        int row = idx >> 5, seg = idx & 31;
        int gr = n0 + row; if (gr >= N) gr = N - 1;
        *(uint4*)&As[row * 264 + seg * 8] = *(const uint4*)&Xagg[(size_t)gr * 256 + seg * 8];
    }
    #pragma unroll
    for (int c = 0; c < 8; c++) {
        int idx = c * 256 + t;
        int row = idx >> 3, seg = idx & 7;
        *(uint4*)&Bs[row * 72 + seg * 8] = *(const uint4*)&W1T[row * 64 + seg * 8];
    }
    __syncthreads();

    int w = t >> 6, l = t & 63;
    int nh = w & 1, th = w >> 1;
    int quad = l >> 4, lm = l & 15;
    int node = n0 + nh * 16 + lm;

    hv8 xf0[2], xf1[2];
    #pragma unroll
    for (int hh = 0; hh < 2; hh++) {
        int h = th * 2 + hh;
        xf0[hh] = *(const hv8*)&As[(nh * 16 + lm) * 264 + h * 64 + quad * 8];
        xf1[hh] = *(const hv8*)&As[(nh * 16 + lm) * 264 + h * 64 + 32 + quad * 8];
    }
    #pragma unroll
    for (int tt2 = 0; tt2 < 8; tt2++) {
        int tt = th * 8 + tt2;
        int hh = tt2 >> 2;
        hv8 wf0 = *(const hv8*)&Bs[(tt * 16 + lm) * 72 + quad * 8];
        hv8 wf1 = *(const hv8*)&Bs[(tt * 16 + lm) * 72 + 32 + quad * 8];
        v4 a = (v4)0.f;
        a = __builtin_amdgcn_mfma_f32_16x16x32_f16(wf0, xf0[hh], a, 0, 0, 0);
        a = __builtin_amdgcn_mfma_f32_16x16x32_f16(wf1, xf1[hh], a, 0, 0, 0);
        int ch = tt * 16 + quad * 4;
        v4 bias = *(const v4*)&b1[ch];
        v4 o = a + bias;
        if (node < N) {
            ushort4 b; b.x = f2h(o[0]); b.y = f2h(o[1]); b.z = f2h(o[2]); b.w = f2h(o[3]);
            *(ushort4*)&Hh[(size_t)node * 256 + ch] = b;
        }
    }
}

// ---------------- Layer 2 GEMM via MFMA (f16) + attention dots ----------------

__global__ __launch_bounds__(256) void gemm2_mfma_kernel(
    const unsigned short* __restrict__ Hh, const unsigned short* __restrict__ W2T,
    const float* __restrict__ att_src, const float* __restrict__ att_dst,
    unsigned short* __restrict__ xh2, float* __restrict__ a_src2, float* __restrict__ a_dst2,
    int N)
{
    __shared__ unsigned short As[64 * 72];
    __shared__ unsigned short Bs[128 * 72];
    int t  = threadIdx.x;
    int n0 = blockIdx.x * 64;
    int w = t >> 6, l = t & 63;
    int quad = l >> 4, lm = l & 15;

    v4 acc[8];
    #pragma unroll
    for (int tt = 0; tt < 8; tt++) acc[tt] = (v4)0.f;

    for (int kt = 0; kt < 256; kt += 64) {
        __syncthreads();
        #pragma unroll
        for (int c = 0; c < 2; c++) {
            int idx = c * 256 + t;
            int row = idx >> 3, seg = idx & 7;
            int gr = n0 + row; if (gr >= N) gr = N - 1;
            *(uint4*)&As[row * 72 + seg * 8] = *(const uint4*)&Hh[(size_t)gr * 256 + kt + seg * 8];
        }
        #pragma unroll
        for (int c = 0; c < 4; c++) {
            int idx = c * 256 + t;
            int row = idx >> 3, seg = idx & 7;
            *(uint4*)&Bs[row * 72 + seg * 8] = *(const uint4*)&W2T[row * 256 + kt + seg * 8];
        }
        __syncthreads();

        hv8 xf0 = *(const hv8*)&As[(w * 16 + lm) * 72 + quad * 8];
        hv8 xf1 = *(const hv8*)&As[(w * 16 + lm) * 72 + 32 + quad * 8];
        #pragma unroll
        for (int tt = 0; tt < 8; tt++) {
            hv8 wf0 = *(const hv8*)&Bs[(tt * 16 + lm) * 72 + quad * 8];
            hv8 wf1 = *(const hv8*)&Bs[(tt * 16 + lm) * 72 + 32 + quad * 8];
            acc[tt] = __builtin_amdgcn_mfma_f32_16x16x32_f16(wf0, xf0, acc[tt], 0, 0, 0);
            acc[tt] = __builtin_amdgcn_mfma_f32_16x16x32_f16(wf1, xf1, acc[tt], 0, 0, 0);
        }
    }

    int node = n0 + w * 16 + lm;
    float vs = 0.f, vd = 0.f;
    #pragma unroll
    for (int tt = 0; tt < 8; tt++) {
        int ch = tt * 16 + quad * 4;
        v4 d = acc[tt];
        v4 as_ = *(const v4*)&att_src[ch];
        v4 ad_ = *(const v4*)&att_dst[ch];
        #pragma unroll
        for (int r = 0; r < 4; r++) { vs += d[r] * as_[r]; vd += d[r] * ad_[r]; }
        ushort4 b; b.x = f2h(d[0]); b.y = f2h(d[1]); b.z = f2h(d[2]); b.w = f2h(d[3]);
        if (node < N) *(ushort4*)&xh2[(size_t)node * 128 + ch] = b;
    }
    vs += __shfl_xor(vs, 16); vs += __shfl_xor(vs, 32);
    vd += __shfl_xor(vd, 16); vd += __shfl_xor(vd, 32);
    if (l < 16 && node < N) { a_src2[node] = vs; a_dst2[node] = vd; }
}

// ---------------- Layer 2 fused softmax+aggregation (16B loads, 4 parities) ----------------

__global__ __launch_bounds__(256) void aggf2_kernel(
    const int* __restrict__ offsets, const int* __restrict__ counts,
    const int* __restrict__ csr_src,
    const float* __restrict__ a_src2, const float* __restrict__ a_dst2,
    const unsigned short* __restrict__ xh2, const float* __restrict__ b2,
    float* __restrict__ out)
{
    int wid  = threadIdx.x >> 6;
    int lane = threadIdx.x & 63;
    int n = blockIdx.x * 4 + wid;
    int beg   = offsets[n];
    int cnt   = counts[n];
    int steps = (offsets[n + 1] - beg) >> 3;
    int hh = lane >> 4;
    int c0 = (lane & 15) * 8;
    float adst = a_dst2[n];

    v4 accL = (v4)0.f, accH = (v4)0.f;
    float den = 0.f;
    int s0[2], s1[2], s2[2];
    float a0[2], a1[2];
    uint4 x0[2], x1[2];

    #pragma unroll
    for (int k = 0; k < 2; k++) s0[k] = csr_src[beg + 4 * k + hh];
    {
        int c1 = (1 < steps) ? 1 : 0;
        #pragma unroll
        for (int k = 0; k < 2; k++) s1[k] = csr_src[beg + c1 * 8 + 4 * k + hh];
    }
    #pragma unroll
    for (int k = 0; k < 2; k++) {
        x0[k] = *(const uint4*)&xh2[(size_t)s0[k] * 128 + c0];
        a0[k] = a_src2[s0[k]];
    }

    for (int i = 0; i < steps; i++) {
        int i2 = (i + 2 < steps) ? i + 2 : steps - 1;
        #pragma unroll
        for (int k = 0; k < 2; k++) s2[k] = csr_src[beg + i2 * 8 + 4 * k + hh];
        if (i + 1 < steps) {
            #pragma unroll
            for (int k = 0; k < 2; k++) {
                x1[k] = *(const uint4*)&xh2[(size_t)s1[k] * 128 + c0];
                a1[k] = a_src2[s1[k]];
            }
        }
        int qb = i * 8 + hh;
        #pragma unroll
        for (int k = 0; k < 2; k++) {
            float e = fminf(leaky02(a0[k] + adst), 80.f);
            float w = (qb + 4 * k < cnt) ? __expf(e) : 0.f;
            den += w;
            v4 lo, hi; unph8(x0[k], lo, hi);
            accL += w * lo; accH += w * hi;
        }
        #pragma unroll
        for (int k = 0; k < 2; k++) {
            x0[k] = x1[k]; a0[k] = a1[k];
            s1[k] = s2[k];
        }
    }

    den += __shfl_xor(den, 16); den += __shfl_xor(den, 32);
    #pragma unroll
    for (int c = 0; c < 4; c++) {
        accL[c] += __shfl_xor(accL[c], 16); accL[c] += __shfl_xor(accL[c], 32);
        accH[c] += __shfl_xor(accH[c], 16); accH[c] += __shfl_xor(accH[c], 32);
    }
    if (lane < 16) {
        float inv = 1.f / den;
        v4 bl = *(const v4*)&b2[c0];
        v4 bh = *(const v4*)&b2[c0 + 4];
        *(v4*)&out[(size_t)n * 128 + c0]     = accL * inv + bl;
        *(v4*)&out[(size_t)n * 128 + c0 + 4] = accH * inv + bh;
    }
}

// ---------------- launcher ----------------

static inline size_t rnd256(size_t x) { return (x + 255) & ~(size_t)255; }

extern "C" void kernel_launch(void* const* d_in, const int* in_sizes, int n_in,
                              void* d_out, int out_size, void* d_ws, size_t ws_size,
                              hipStream_t stream) {
    const float* X   = (const float*)d_in[0];
    const int*   ei  = (const int*)d_in[1];
    const float* W1  = (const float*)d_in[2];
    const float* as1 = (const float*)d_in[3];
    const float* ad1 = (const float*)d_in[4];
    const float* b1  = (const float*)d_in[5];
    const float* W2  = (const float*)d_in[6];
    const float* as2 = (const float*)d_in[7];
    const float* ad2 = (const float*)d_in[8];
    const float* b2  = (const float*)d_in[9];
    float* out = (float*)d_out;

    const int N = in_sizes[0] / 64;   // 50000
    const int E = in_sizes[1] / 2;    // 800000
    const int* srcArr = ei;
    const int* dstArr = ei + E;
    const size_t CSRMAX = (size_t)E + 8 * (size_t)N;
    const int NB = (N + 1023) / 1024;
    const int EB = (E + N + 255) / 256;
    const int PB = (N + 255) / 256;
    const int XB = (N * 64 / 8 + 255) / 256;
    const int IB = (N + 255) / 256;

    char* w = (char*)d_ws;
    unsigned short* Xh     = (unsigned short*)w;  w += rnd256((size_t)N * 64 * 2);
    unsigned short* W1T    = (unsigned short*)w;  w += rnd256((size_t)256 * 64 * 2);
    unsigned short* W2T    = (unsigned short*)w;  w += rnd256((size_t)128 * 256 * 2);
    float* vsrc    = (float*)w;  w += rnd256(256 * 4);
    float* vdst    = (float*)w;  w += rnd256(256 * 4);
    unsigned short* Xagg   = (unsigned short*)w;  w += rnd256((size_t)N * 256 * 2);
    unsigned short* Hh     = (unsigned short*)w;  w += rnd256((size_t)N * 256 * 2);
    float* a_src1  = (float*)w;  w += rnd256((size_t)N * 4 * 4);
    float* a_dst1  = (float*)w;  w += rnd256((size_t)N * 4 * 4);
    float* a_src2v = (float*)w;  w += rnd256((size_t)N * 4);
    float* a_dst2v = (float*)w;  w += rnd256((size_t)N * 4);
    int*   counts  = (int*)w;    w += rnd256((size_t)N * 4);
    int*   offsets = (int*)w;    w += rnd256((size_t)(N + 1) * 4);
    int*   cursor  = (int*)w;    w += rnd256((size_t)N * 4);
    int*   blockSums = (int*)w;  w += rnd256((size_t)NB * 4);
    int*   csr_src = (int*)w;    w += rnd256(CSRMAX * 4);
    unsigned short* xh2 = Xagg;  // Xagg dead after gemmH; reuse for layer-2 features

    // prep (conv + v-vectors + CSR init fused)
    conv_init_kernel<<<XB + 64 + 128 + IB + 2, 256, 0, stream>>>(
        X, W1, W2, as1, ad1, Xh, W1T, W2T, vsrc, vdst, counts, cursor, XB, N * 64, N, IB);
    // CSR build
    hist_kernel<<<(E + 255) / 256, 256, 0, stream>>>(dstArr, counts, E);
    scanA_kernel<<<NB, 256, 0, stream>>>(counts, blockSums, N);
    scanC_kernel<<<NB, 256, 0, stream>>>(counts, blockSums, offsets, N, NB);
    scatter_kernel<<<EB + PB, 256, 0, stream>>>(srcArr, dstArr, offsets, counts, cursor,
                                                csr_src, E, N, EB);
    // layer 1 (flipped: attdot -> aggregate X -> GEMM)
    attdot_kernel<<<(N + 31) / 32, 256, 0, stream>>>(Xh, vsrc, vdst, a_src1, a_dst1, N);
    aggX_kernel<<<N / 4, 256, 0, stream>>>(offsets, counts, csr_src, a_src1, a_dst1, Xh, Xagg);
    gemmH_kernel<<<(N + 31) / 32, 256, 0, stream>>>(Xagg, W1T, b1, Hh, N);
    // layer 2
    gemm2_mfma_kernel<<<(N + 63) / 64, 256, 0, stream>>>(Hh, W2T, as2, ad2, xh2,
                                                         a_src2v, a_dst2v, N);
    aggf2_kernel<<<N / 4, 256, 0, stream>>>(offsets, counts, csr_src, a_src2v, a_dst2v,
                                            xh2, b2, out);
}

// Round 9
// 309.080 us; speedup vs baseline: 2.6915x; 1.0262x over previous
//
#include <hip/hip_runtime.h>
#include <hip/hip_bf16.h>
#include <hip/hip_fp16.h>

typedef float v4 __attribute__((ext_vector_type(4)));
typedef _Float16 hv8 __attribute__((ext_vector_type(8)));
typedef _Float16 h2 __attribute__((ext_vector_type(2)));
typedef unsigned int u32x4 __attribute__((ext_vector_type(4)));
typedef unsigned short u16x4 __attribute__((ext_vector_type(4)));

__device__ __forceinline__ unsigned short f2h(float f) {
    _Float16 h = (_Float16)f;
    return __builtin_bit_cast(unsigned short, h);
}
// uint4 = 8 f16 (memory order) -> two v4 fp32
__device__ __forceinline__ void unph8(uint4 u, v4& lo, v4& hi) {
    h2 a = __builtin_bit_cast(h2, u.x);
    h2 b = __builtin_bit_cast(h2, u.y);
    h2 c = __builtin_bit_cast(h2, u.z);
    h2 d = __builtin_bit_cast(h2, u.w);
    lo[0] = (float)a[0]; lo[1] = (float)a[1]; lo[2] = (float)b[0]; lo[3] = (float)b[1];
    hi[0] = (float)c[0]; hi[1] = (float)c[1]; hi[2] = (float)d[0]; hi[3] = (float)d[1];
}
__device__ __forceinline__ float leaky02(float x) { return x >= 0.f ? x : 0.2f * x; }

// ---- prep: X->f16, W1T/W2T f16, v = W1·att (fp32), counts/cursor init ----

__global__ __launch_bounds__(256) void conv_init_kernel(
    const float* __restrict__ X, const float* __restrict__ W1, const float* __restrict__ W2,
    const float* __restrict__ as1, const float* __restrict__ ad1,
    unsigned short* __restrict__ Xh, unsigned short* __restrict__ W1T,
    unsigned short* __restrict__ W2T, float* __restrict__ vsrc, float* __restrict__ vdst,
    int* __restrict__ counts, int* __restrict__ cursor,
    int XB, int NX, int N, int IB)
{
    int b = blockIdx.x, t = threadIdx.x;
    if (b < XB) {
        int i = (b * 256 + t) * 8;
        if (i < NX) {
            float4 a = *(const float4*)&X[i];
            float4 c = *(const float4*)&X[i + 4];
            ushort4 r0; r0.x = f2h(a.x); r0.y = f2h(a.y); r0.z = f2h(a.z); r0.w = f2h(a.w);
            ushort4 r1; r1.x = f2h(c.x); r1.y = f2h(c.y); r1.z = f2h(c.z); r1.w = f2h(c.w);
            *(ushort4*)&Xh[i] = r0;
            *(ushort4*)&Xh[i + 4] = r1;
        }
    } else if (b < XB + 64) {
        int id = (b - XB) * 256 + t;      // [256 out][64 k]
        int j = id >> 6, k = id & 63;
        W1T[id] = f2h(W1[k * 256 + j]);
    } else if (b < XB + 64 + 128) {
        int id = (b - XB - 64) * 256 + t; // [128 out][256 k]
        int j = id >> 8, k = id & 255;
        W2T[id] = f2h(W2[k * 128 + j]);
    } else if (b < XB + 64 + 128 + IB) {
        int i = (b - XB - 64 - 128) * 256 + t;
        if (i < N) { counts[i] = 1; cursor[i] = 0; }
    } else {
        int vb = b - (XB + 64 + 128 + IB);
        const float* att = vb ? ad1 : as1;
        float* vout = vb ? vdst : vsrc;
        int h = t >> 6, k = t & 63;
        float s = 0.f;
        const float* wrow = &W1[k * 256 + h * 64];
        const float* arow = &att[h * 64];
        #pragma unroll 8
        for (int c = 0; c < 64; c++) s += wrow[c] * arow[c];
        vout[t] = s;
    }
}

// ---------------- CSR build (degree padded to multiple of 8) ----------------

__global__ __launch_bounds__(256) void hist_kernel(const int* __restrict__ dst, int* counts, int E) {
    int e = blockIdx.x * 256 + threadIdx.x;
    if (e < E) atomicAdd(&counts[dst[e]], 1);
}

__global__ __launch_bounds__(256) void scanA_kernel(const int* __restrict__ counts,
                                                    int* __restrict__ blockSums, int n) {
    __shared__ int red[256];
    int b = blockIdx.x, t = threadIdx.x;
    int base = b * 1024;
    int s = 0;
    #pragma unroll
    for (int j = 0; j < 4; j++) {
        int i = base + j * 256 + t;
        if (i < n) s += (counts[i] + 7) & ~7;
    }
    red[t] = s; __syncthreads();
    for (int off = 128; off; off >>= 1) { if (t < off) red[t] += red[t + off]; __syncthreads(); }
    if (t == 0) blockSums[b] = red[0];
}

__global__ __launch_bounds__(256) void scanC_kernel(const int* __restrict__ counts,
                                                    const int* __restrict__ blockSums,
                                                    int* __restrict__ offsets, int n, int nb) {
    __shared__ int red[256];
    __shared__ int base_s;
    int b = blockIdx.x, t = threadIdx.x;
    if (t < 64) {
        int v = (t < nb) ? blockSums[t] : 0;
        #pragma unroll
        for (int off = 1; off < 64; off <<= 1) {
            int u = __shfl_up(v, off);
            if (t >= off) v += u;
        }
        int basev = (b == 0) ? 0 : __shfl(v, b - 1);
        int tot = __shfl(v, nb - 1);
        if (t == 0) {
            base_s = basev;
            if (b == 0) offsets[n] = tot;
        }
    }
    int base = b * 1024;
    int c[4]; int s = 0;
    #pragma unroll
    for (int j = 0; j < 4; j++) {
        int i = base + t * 4 + j;
        c[j] = (i < n) ? ((counts[i] + 7) & ~7) : 0;
        s += c[j];
    }
    red[t] = s; __syncthreads();
    for (int off = 1; off < 256; off <<= 1) {
        int u = (t >= off) ? red[t - off] : 0;
        __syncthreads();
        red[t] += u;
        __syncthreads();
    }
    int excl = red[t] - s + base_s;
    #pragma unroll
    for (int j = 0; j < 4; j++) {
        int i = base + t * 4 + j;
        if (i < n) offsets[i] = excl;
        excl += c[j];
    }
}

__global__ __launch_bounds__(256) void scatter_kernel(const int* __restrict__ src,
                                                      const int* __restrict__ dst,
                                                      const int* __restrict__ offsets,
                                                      const int* __restrict__ counts,
                                                      int* cursor, int* csr_src,
                                                      int E, int N, int EB) {
    if ((int)blockIdx.x < EB) {
        int id = blockIdx.x * 256 + threadIdx.x;
        if (id >= E + N) return;
        int d, s;
        if (id < E) { d = dst[id]; s = src[id]; }
        else        { d = id - E; s = d; }      // self-loop
        int pos = offsets[d] + atomicAdd(&cursor[d], 1);
        csr_src[pos] = s;
    } else {
        int i = (blockIdx.x - EB) * 256 + threadIdx.x;
        if (i >= N) return;
        int beg = offsets[i];
        int cnt = counts[i];
        int degp = (cnt + 7) & ~7;
        for (int q = cnt; q < degp; q++) csr_src[beg + q] = i;  // pad -> self (w masked 0)
    }
}

// ---------------- attention dots: a_src1/a_dst1 = Xh · v ----------------

__global__ __launch_bounds__(256) void attdot_kernel(
    const unsigned short* __restrict__ Xh, const float* __restrict__ vsrc,
    const float* __restrict__ vdst, float* __restrict__ a_src1, float* __restrict__ a_dst1,
    int N)
{
    __shared__ float vs[256], vd[256];
    int t = threadIdx.x;
    vs[t] = vsrc[t]; vd[t] = vdst[t];
    __syncthreads();
    int w = t >> 6, lane = t & 63;
    int nd = lane >> 3, sub = lane & 7, kc = sub * 8;
    int node = blockIdx.x * 32 + w * 8 + nd;
    if (node >= N) node = N - 1;
    uint4 x = *(const uint4*)&Xh[(size_t)node * 64 + kc];
    v4 lo, hi; unph8(x, lo, hi);
    float ps[4], pd[4];
    #pragma unroll
    for (int h = 0; h < 4; h++) {
        float s = 0.f, d = 0.f;
        #pragma unroll
        for (int j = 0; j < 4; j++) {
            s += lo[j] * vs[h * 64 + kc + j];     d += lo[j] * vd[h * 64 + kc + j];
            s += hi[j] * vs[h * 64 + kc + 4 + j]; d += hi[j] * vd[h * 64 + kc + 4 + j];
        }
        ps[h] = s; pd[h] = d;
    }
    #pragma unroll
    for (int off = 1; off < 8; off <<= 1)
        #pragma unroll
        for (int h = 0; h < 4; h++) {
            ps[h] += __shfl_xor(ps[h], off);
            pd[h] += __shfl_xor(pd[h], off);
        }
    if (sub == 0) {
        v4 o0; o0[0] = ps[0]; o0[1] = ps[1]; o0[2] = ps[2]; o0[3] = ps[3];
        v4 o1; o1[0] = pd[0]; o1[1] = pd[1]; o1[2] = pd[2]; o1[3] = pd[3];
        *(v4*)&a_src1[node * 4] = o0;
        *(v4*)&a_dst1[node * 4] = o1;
    }
}

// ---------------- Layer 1 fused softmax + X-aggregation ----------------
// 2 nodes per wave: nd=lane>>5; 4 edge-parities p=(lane>>3)&3; 8 ch-lanes sub=lane&7.
// steps = degp/4 (>=2); 3-stage pipeline; tail = 2 shuffle levels (xor 8,16).

__global__ __launch_bounds__(256) void aggX_kernel(
    const int* __restrict__ offsets, const int* __restrict__ counts,
    const int* __restrict__ csr_src,
    const float* __restrict__ a_src1, const float* __restrict__ a_dst1,
    const unsigned short* __restrict__ Xh, unsigned short* __restrict__ Xagg, int N)
{
    int wid  = threadIdx.x >> 6;
    int lane = threadIdx.x & 63;
    int nd = lane >> 5;
    int p = (lane >> 3) & 3, sub = lane & 7, kc = sub * 8;
    int n = blockIdx.x * 8 + wid * 2 + nd;
    if (n >= N) return;
    int beg   = offsets[n];
    int cnt   = counts[n];
    int steps = (offsets[n + 1] - beg) >> 2;   // 4 edges per step, >= 2
    v4 adst = *(const v4*)&a_dst1[n * 4];

    v4 accL[4], accH[4];
    #pragma unroll
    for (int h = 0; h < 4; h++) { accL[h] = (v4)0.f; accH[h] = (v4)0.f; }
    v4 den = (v4)0.f;

    int s0, s1, s2;
    uint4 x0, x1;
    v4 a0, a1;

    s0 = __builtin_nontemporal_load(&csr_src[beg + p]);
    s1 = __builtin_nontemporal_load(&csr_src[beg + 4 + p]);
    x0 = *(const uint4*)&Xh[(size_t)s0 * 64 + kc];
    a0 = *(const v4*)&a_src1[s0 * 4];

    for (int i = 0; i < steps; i++) {
        int i2 = (i + 2 < steps) ? i + 2 : steps - 1;
        s2 = __builtin_nontemporal_load(&csr_src[beg + i2 * 4 + p]);
        if (i + 1 < steps) {
            x1 = *(const uint4*)&Xh[(size_t)s1 * 64 + kc];
            a1 = *(const v4*)&a_src1[s1 * 4];
        }
        bool valid = (i * 4 + p) < cnt;
        v4 lo, hi; unph8(x0, lo, hi);
        #pragma unroll
        for (int h = 0; h < 4; h++) {
            float e = fminf(leaky02(a0[h] + adst[h]), 80.f);
            float w = valid ? __expf(e) : 0.f;
            den[h] += w;
            accL[h] += w * lo;
            accH[h] += w * hi;
        }
        x0 = x1; a0 = a1; s1 = s2;
    }

    // reduce across 4 parities (lane bits 3,4) within each 32-lane half
    #pragma unroll
    for (int off = 8; off < 32; off <<= 1) {
        #pragma unroll
        for (int h = 0; h < 4; h++) {
            den[h] += __shfl_xor(den[h], off);
            #pragma unroll
            for (int c = 0; c < 4; c++) {
                accL[h][c] += __shfl_xor(accL[h][c], off);
                accH[h][c] += __shfl_xor(accH[h][c], off);
            }
        }
    }
    if (p == 0) {
        #pragma unroll
        for (int h = 0; h < 4; h++) {
            float inv = 1.f / den[h];
            v4 oL = accL[h] * inv, oH = accH[h] * inv;
            u32x4 pk;
            pk[0] = (unsigned)f2h(oL[0]) | ((unsigned)f2h(oL[1]) << 16);
            pk[1] = (unsigned)f2h(oL[2]) | ((unsigned)f2h(oL[3]) << 16);
            pk[2] = (unsigned)f2h(oH[0]) | ((unsigned)f2h(oH[1]) << 16);
            pk[3] = (unsigned)f2h(oH[2]) | ((unsigned)f2h(oH[3]) << 16);
            __builtin_nontemporal_store(pk, (u32x4*)&Xagg[(size_t)n * 256 + h * 64 + kc]);
        }
    }
}

// ---------------- H = Xagg (per-head) · W1 + b1, f16 out ----------------

__global__ __launch_bounds__(256) void gemmH_kernel(
    const unsigned short* __restrict__ Xagg, const unsigned short* __restrict__ W1T,
    const float* __restrict__ b1, unsigned short* __restrict__ Hh, int N)
{
    __shared__ unsigned short As[32 * 264];
    __shared__ unsigned short Bs[256 * 72];
    int t  = threadIdx.x;
    int n0 = blockIdx.x * 32;

    #pragma unroll
    for (int c = 0; c < 4; c++) {
        int idx = c * 256 + t;
        int row = idx >> 5, seg = idx & 31;
        int gr = n0 + row; if (gr >= N) gr = N - 1;
        *(uint4*)&As[row * 264 + seg * 8] = *(const uint4*)&Xagg[(size_t)gr * 256 + seg * 8];
    }
    #pragma unroll
    for (int c = 0; c < 8; c++) {
        int idx = c * 256 + t;
        int row = idx >> 3, seg = idx & 7;
        *(uint4*)&Bs[row * 72 + seg * 8] = *(const uint4*)&W1T[row * 64 + seg * 8];
    }
    __syncthreads();

    int w = t >> 6, l = t & 63;
    int nh = w & 1, th = w >> 1;
    int quad = l >> 4, lm = l & 15;
    int node = n0 + nh * 16 + lm;

    hv8 xf0[2], xf1[2];
    #pragma unroll
    for (int hh = 0; hh < 2; hh++) {
        int h = th * 2 + hh;
        xf0[hh] = *(const hv8*)&As[(nh * 16 + lm) * 264 + h * 64 + quad * 8];
        xf1[hh] = *(const hv8*)&As[(nh * 16 + lm) * 264 + h * 64 + 32 + quad * 8];
    }
    #pragma unroll
    for (int tt2 = 0; tt2 < 8; tt2++) {
        int tt = th * 8 + tt2;
        int hh = tt2 >> 2;
        hv8 wf0 = *(const hv8*)&Bs[(tt * 16 + lm) * 72 + quad * 8];
        hv8 wf1 = *(const hv8*)&Bs[(tt * 16 + lm) * 72 + 32 + quad * 8];
        v4 a = (v4)0.f;
        a = __builtin_amdgcn_mfma_f32_16x16x32_f16(wf0, xf0[hh], a, 0, 0, 0);
        a = __builtin_amdgcn_mfma_f32_16x16x32_f16(wf1, xf1[hh], a, 0, 0, 0);
        int ch = tt * 16 + quad * 4;
        v4 bias = *(const v4*)&b1[ch];
        v4 o = a + bias;
        if (node < N) {
            u16x4 b;
            b[0] = f2h(o[0]); b[1] = f2h(o[1]); b[2] = f2h(o[2]); b[3] = f2h(o[3]);
            __builtin_nontemporal_store(b, (u16x4*)&Hh[(size_t)node * 256 + ch]);
        }
    }
}

// ---------------- Layer 2 GEMM via MFMA (f16) + attention dots ----------------

__global__ __launch_bounds__(256) void gemm2_mfma_kernel(
    const unsigned short* __restrict__ Hh, const unsigned short* __restrict__ W2T,
    const float* __restrict__ att_src, const float* __restrict__ att_dst,
    unsigned short* __restrict__ xh2, float* __restrict__ a_src2, float* __restrict__ a_dst2,
    int N)
{
    __shared__ unsigned short As[64 * 72];
    __shared__ unsigned short Bs[128 * 72];
    int t  = threadIdx.x;
    int n0 = blockIdx.x * 64;
    int w = t >> 6, l = t & 63;
    int quad = l >> 4, lm = l & 15;

    v4 acc[8];
    #pragma unroll
    for (int tt = 0; tt < 8; tt++) acc[tt] = (v4)0.f;

    for (int kt = 0; kt < 256; kt += 64) {
        __syncthreads();
        #pragma unroll
        for (int c = 0; c < 2; c++) {
            int idx = c * 256 + t;
            int row = idx >> 3, seg = idx & 7;
            int gr = n0 + row; if (gr >= N) gr = N - 1;
            *(uint4*)&As[row * 72 + seg * 8] = *(const uint4*)&Hh[(size_t)gr * 256 + kt + seg * 8];
        }
        #pragma unroll
        for (int c = 0; c < 4; c++) {
            int idx = c * 256 + t;
            int row = idx >> 3, seg = idx & 7;
            *(uint4*)&Bs[row * 72 + seg * 8] = *(const uint4*)&W2T[row * 256 + kt + seg * 8];
        }
        __syncthreads();

        hv8 xf0 = *(const hv8*)&As[(w * 16 + lm) * 72 + quad * 8];
        hv8 xf1 = *(const hv8*)&As[(w * 16 + lm) * 72 + 32 + quad * 8];
        #pragma unroll
        for (int tt = 0; tt < 8; tt++) {
            hv8 wf0 = *(const hv8*)&Bs[(tt * 16 + lm) * 72 + quad * 8];
            hv8 wf1 = *(const hv8*)&Bs[(tt * 16 + lm) * 72 + 32 + quad * 8];
            acc[tt] = __builtin_amdgcn_mfma_f32_16x16x32_f16(wf0, xf0, acc[tt], 0, 0, 0);
            acc[tt] = __builtin_amdgcn_mfma_f32_16x16x32_f16(wf1, xf1, acc[tt], 0, 0, 0);
        }
    }

    int node = n0 + w * 16 + lm;
    float vs = 0.f, vd = 0.f;
    #pragma unroll
    for (int tt = 0; tt < 8; tt++) {
        int ch = tt * 16 + quad * 4;
        v4 d = acc[tt];
        v4 as_ = *(const v4*)&att_src[ch];
        v4 ad_ = *(const v4*)&att_dst[ch];
        #pragma unroll
        for (int r = 0; r < 4; r++) { vs += d[r] * as_[r]; vd += d[r] * ad_[r]; }
        ushort4 b; b.x = f2h(d[0]); b.y = f2h(d[1]); b.z = f2h(d[2]); b.w = f2h(d[3]);
        if (node < N) *(ushort4*)&xh2[(size_t)node * 128 + ch] = b;   // cached: gather target
    }
    vs += __shfl_xor(vs, 16); vs += __shfl_xor(vs, 32);
    vd += __shfl_xor(vd, 16); vd += __shfl_xor(vd, 32);
    if (l < 16 && node < N) { a_src2[node] = vs; a_dst2[node] = vd; }
}

// ---------------- Layer 2 fused softmax+aggregation ----------------
// 2 nodes per wave: nd=lane>>5; 2 parities p=(lane>>4)&1; 16 ch-lanes (128 ch).
// steps = degp/2 (>=4); tail = 1 shuffle level (xor 16).

__global__ __launch_bounds__(256) void aggf2_kernel(
    const int* __restrict__ offsets, const int* __restrict__ counts,
    const int* __restrict__ csr_src,
    const float* __restrict__ a_src2, const float* __restrict__ a_dst2,
    const unsigned short* __restrict__ xh2, const float* __restrict__ b2,
    float* __restrict__ out, int N)
{
    int wid  = threadIdx.x >> 6;
    int lane = threadIdx.x & 63;
    int nd = lane >> 5;
    int p = (lane >> 4) & 1;
    int c0 = (lane & 15) * 8;
    int n = blockIdx.x * 8 + wid * 2 + nd;
    if (n >= N) return;
    int beg   = offsets[n];
    int cnt   = counts[n];
    int steps = (offsets[n + 1] - beg) >> 1;   // 2 edges per step, >= 4
    float adst = a_dst2[n];

    v4 accL = (v4)0.f, accH = (v4)0.f;
    float den = 0.f;
    int s0, s1, s2;
    float a0, a1;
    uint4 x0, x1;

    s0 = __builtin_nontemporal_load(&csr_src[beg + p]);
    s1 = __builtin_nontemporal_load(&csr_src[beg + 2 + p]);
    x0 = *(const uint4*)&xh2[(size_t)s0 * 128 + c0];
    a0 = a_src2[s0];

    for (int i = 0; i < steps; i++) {
        int i2 = (i + 2 < steps) ? i + 2 : steps - 1;
        s2 = __builtin_nontemporal_load(&csr_src[beg + i2 * 2 + p]);
        if (i + 1 < steps) {
            x1 = *(const uint4*)&xh2[(size_t)s1 * 128 + c0];
            a1 = a_src2[s1];
        }
        float e = fminf(leaky02(a0 + adst), 80.f);
        float w = ((i * 2 + p) < cnt) ? __expf(e) : 0.f;
        den += w;
        v4 lo, hi; unph8(x0, lo, hi);
        accL += w * lo; accH += w * hi;
        x0 = x1; a0 = a1; s1 = s2;
    }

    den += __shfl_xor(den, 16);
    #pragma unroll
    for (int c = 0; c < 4; c++) {
        accL[c] += __shfl_xor(accL[c], 16);
        accH[c] += __shfl_xor(accH[c], 16);
    }
    if (p == 0) {
        float inv = 1.f / den;
        v4 bl = *(const v4*)&b2[c0];
        v4 bh = *(const v4*)&b2[c0 + 4];
        v4 oL = accL * inv + bl;
        v4 oH = accH * inv + bh;
        __builtin_nontemporal_store(oL, (v4*)&out[(size_t)n * 128 + c0]);
        __builtin_nontemporal_store(oH, (v4*)&out[(size_t)n * 128 + c0 + 4]);
    }
}

// ---------------- launcher ----------------

static inline size_t rnd256(size_t x) { return (x + 255) & ~(size_t)255; }

extern "C" void kernel_launch(void* const* d_in, const int* in_sizes, int n_in,
                              void* d_out, int out_size, void* d_ws, size_t ws_size,
                              hipStream_t stream) {
    const float* X   = (const float*)d_in[0];
    const int*   ei  = (const int*)d_in[1];
    const float* W1  = (const float*)d_in[2];
    const float* as1 = (const float*)d_in[3];
    const float* ad1 = (const float*)d_in[4];
    const float* b1  = (const float*)d_in[5];
    const float* W2  = (const float*)d_in[6];
    const float* as2 = (const float*)d_in[7];
    const float* ad2 = (const float*)d_in[8];
    const float* b2  = (const float*)d_in[9];
    float* out = (float*)d_out;

    const int N = in_sizes[0] / 64;   // 50000
    const int E = in_sizes[1] / 2;    // 800000
    const int* srcArr = ei;
    const int* dstArr = ei + E;
    const size_t CSRMAX = (size_t)E + 8 * (size_t)N;
    const int NB = (N + 1023) / 1024;
    const int EB = (E + N + 255) / 256;
    const int PB = (N + 255) / 256;
    const int XB = (N * 64 / 8 + 255) / 256;
    const int IB = (N + 255) / 256;

    char* w = (char*)d_ws;
    unsigned short* Xh     = (unsigned short*)w;  w += rnd256((size_t)N * 64 * 2);
    unsigned short* W1T    = (unsigned short*)w;  w += rnd256((size_t)256 * 64 * 2);
    unsigned short* W2T    = (unsigned short*)w;  w += rnd256((size_t)128 * 256 * 2);
    float* vsrc    = (float*)w;  w += rnd256(256 * 4);
    float* vdst    = (float*)w;  w += rnd256(256 * 4);
    unsigned short* Xagg   = (unsigned short*)w;  w += rnd256((size_t)N * 256 * 2);
    unsigned short* Hh     = (unsigned short*)w;  w += rnd256((size_t)N * 256 * 2);
    float* a_src1  = (float*)w;  w += rnd256((size_t)N * 4 * 4);
    float* a_dst1  = (float*)w;  w += rnd256((size_t)N * 4 * 4);
    float* a_src2v = (float*)w;  w += rnd256((size_t)N * 4);
    float* a_dst2v = (float*)w;  w += rnd256((size_t)N * 4);
    int*   counts  = (int*)w;    w += rnd256((size_t)N * 4);
    int*   offsets = (int*)w;    w += rnd256((size_t)(N + 1) * 4);
    int*   cursor  = (int*)w;    w += rnd256((size_t)N * 4);
    int*   blockSums = (int*)w;  w += rnd256((size_t)NB * 4);
    int*   csr_src = (int*)w;    w += rnd256(CSRMAX * 4);
    unsigned short* xh2 = Xagg;  // Xagg dead after gemmH; reuse for layer-2 features

    // prep (conv + v-vectors + CSR init fused)
    conv_init_kernel<<<XB + 64 + 128 + IB + 2, 256, 0, stream>>>(
        X, W1, W2, as1, ad1, Xh, W1T, W2T, vsrc, vdst, counts, cursor, XB, N * 64, N, IB);
    // CSR build
    hist_kernel<<<(E + 255) / 256, 256, 0, stream>>>(dstArr, counts, E);
    scanA_kernel<<<NB, 256, 0, stream>>>(counts, blockSums, N);
    scanC_kernel<<<NB, 256, 0, stream>>>(counts, blockSums, offsets, N, NB);
    scatter_kernel<<<EB + PB, 256, 0, stream>>>(srcArr, dstArr, offsets, counts, cursor,
                                                csr_src, E, N, EB);
    // layer 1 (flipped: attdot -> aggregate X -> GEMM)
    attdot_kernel<<<(N + 31) / 32, 256, 0, stream>>>(Xh, vsrc, vdst, a_src1, a_dst1, N);
    aggX_kernel<<<(N + 7) / 8, 256, 0, stream>>>(offsets, counts, csr_src, a_src1, a_dst1,
                                                 Xh, Xagg, N);
    gemmH_kernel<<<(N + 31) / 32, 256, 0, stream>>>(Xagg, W1T, b1, Hh, N);
    // layer 2
    gemm2_mfma_kernel<<<(N + 63) / 64, 256, 0, stream>>>(Hh, W2T, as2, ad2, xh2,
                                                         a_src2v, a_dst2v, N);
    aggf2_kernel<<<(N + 7) / 8, 256, 0, stream>>>(offsets, counts, csr_src, a_src2v, a_dst2v,
                                                  xh2, b2, out, N);
}